// Round 2
// baseline (401.745 us; speedup 1.0000x reference)
//
#include <hip/hip_runtime.h>

#define BATCH 8
#define SEQ   2048
#define DIM   1024   // D == H == 1024

typedef __attribute__((ext_vector_type(8)))  short short8;
typedef __attribute__((ext_vector_type(4)))  short short4v;
typedef __attribute__((ext_vector_type(4)))  float floatx4;
typedef __attribute__((ext_vector_type(16))) float floatx16;

__device__ __forceinline__ unsigned short f32_to_bf16(float f) {
    union { float f; unsigned int u; } x; x.f = f;
    unsigned int r = x.u + 0x7fffu + ((x.u >> 16) & 1u);
    return (unsigned short)(r >> 16);
}

__device__ __forceinline__ float bf16_to_f32(unsigned short h) {
    union { unsigned int u; float f; } x; x.u = ((unsigned int)h) << 16;
    return x.f;
}

// async 16B/lane global->LDS. LDS base wave-uniform; HW scatters lane i at base+16*i.
__device__ __forceinline__ void async_load16(const void* g, void* l) {
    __builtin_amdgcn_global_load_lds(
        (const __attribute__((address_space(1))) void*)g,
        (__attribute__((address_space(3))) void*)l, 16, 0, 0);
}

#define CFENCE asm volatile("" ::: "memory")
#define BARF() do { CFENCE; __builtin_amdgcn_s_barrier(); CFENCE; } while (0)
#define WAIT_LGKM0 do { asm volatile("s_waitcnt lgkmcnt(0)" ::: "memory"); \
                        __builtin_amdgcn_sched_barrier(0); } while (0)

// ---------------------------------------------------------------------------
// per-batch compaction: idx[b][0..cnt) = rows with mask>0.5 (ascending),
// pads idx[cnt..SEQ) = 0; cnt[b]; padcnt[b] = round-up-128(cnt).
// ---------------------------------------------------------------------------
__global__ __launch_bounds__(256) void build_idx(
    const float* __restrict__ mask, int* __restrict__ idx,
    int* __restrict__ cnt, int* __restrict__ padcnt)
{
    const int b = blockIdx.x;
    const int t = threadIdx.x;
    const float* mb = mask + b * SEQ;
    int flags[8]; int c = 0;
#pragma unroll
    for (int j = 0; j < 8; ++j) {
        flags[j] = (mb[t * 8 + j] > 0.5f) ? 1 : 0;
        c += flags[j];
    }
    int sc = c;                       // inclusive scan within wave
    for (int o = 1; o < 64; o <<= 1) {
        int v = __shfl_up(sc, o);
        if ((t & 63) >= o) sc += v;
    }
    __shared__ int wtot[4];
    const int lane = t & 63, wave = t >> 6;
    if (lane == 63) wtot[wave] = sc;
    __syncthreads();
    int woff = 0;
    for (int w = 0; w < wave; ++w) woff += wtot[w];
    int p = woff + sc - c;            // exclusive offset
#pragma unroll
    for (int j = 0; j < 8; ++j)
        if (flags[j]) idx[b * SEQ + (p++)] = t * 8 + j;
    __syncthreads();
    const int total = wtot[0] + wtot[1] + wtot[2] + wtot[3];
    if (t == 0) { cnt[b] = total; padcnt[b] = (total + 127) & ~127; }
    for (int q = total + t; q < SEQ; q += 256) idx[b * SEQ + q] = 0;
}

// ---------------------------------------------------------------------------
// gather unmasked input_q rows (f32) -> compacted bf16 rows
// ---------------------------------------------------------------------------
__global__ __launch_bounds__(256) void gather_cvt_q(
    const float* __restrict__ xq, const int* __restrict__ idx,
    const int* __restrict__ padcnt, unsigned short* __restrict__ qc)
{
    const int b = blockIdx.y;
    const int rc = blockIdx.x;
    if (rc >= padcnt[b]) return;
    const int src = idx[b * SEQ + rc];
    const float* s = xq + ((long)b * SEQ + src) * DIM + threadIdx.x * 4;
    unsigned short* d = qc + ((long)b * SEQ + rc) * DIM + threadIdx.x * 4;
    floatx4 v = *(const floatx4*)s;
    short4v w;
#pragma unroll
    for (int j = 0; j < 4; ++j) w[j] = (short)f32_to_bf16(v[j]);
    *(short4v*)d = w;
}

// ---------------------------------------------------------------------------
// fused single pass over input_k:
//   kbf = bf16(input_k)  (straight layout)
//   Vt  = bf16(input_k)^T per batch (DIM x SEQ)
//   mavg += masked column partial sums
// grid (DIM/32, SEQ/32, BATCH), block 256 (32x8)
// ---------------------------------------------------------------------------
__global__ __launch_bounds__(256) void prep_kv(
    const float* __restrict__ xk, const float* __restrict__ mask,
    unsigned short* __restrict__ kbf, unsigned short* __restrict__ Vt,
    float* __restrict__ mavg)
{
    __shared__ float tile[32][33];
    __shared__ float msk[32];
    __shared__ float csum[8][32];
    const int b  = blockIdx.z;
    const int c0 = blockIdx.x * 32;   // dim cols
    const int r0 = blockIdx.y * 32;   // seq rows
    const int tx = threadIdx.x & 31, ty = threadIdx.x >> 5;   // ty 0..7
    const float* xb = xk + (long)b * SEQ * DIM;
    unsigned short* kb = kbf + (long)b * SEQ * DIM;
    unsigned short* vb = Vt + (long)b * DIM * SEQ;

    if (threadIdx.x < 32) msk[threadIdx.x] = mask[b * SEQ + r0 + threadIdx.x];

    float v[4];
#pragma unroll
    for (int i = 0; i < 4; ++i) {
        const int r = ty + i * 8;
        v[i] = xb[(long)(r0 + r) * DIM + c0 + tx];
        tile[r][tx] = v[i];
        kb[(long)(r0 + r) * DIM + c0 + tx] = f32_to_bf16(v[i]);
    }
    __syncthreads();

    float s = 0.f;
#pragma unroll
    for (int i = 0; i < 4; ++i) {
        const int r = ty + i * 8;
        s += (msk[r] <= 0.5f) ? v[i] : 0.f;
    }
    csum[ty][tx] = s;

#pragma unroll
    for (int i = 0; i < 4; ++i) {
        const int c = ty + i * 8;
        vb[(long)(c0 + c) * SEQ + r0 + tx] = f32_to_bf16(tile[tx][c]);
    }
    __syncthreads();
    if (ty == 0) {
        float t = 0.f;
#pragma unroll
        for (int j = 0; j < 8; ++j) t += csum[j][tx];
        atomicAdd(&mavg[b * DIM + c0 + tx], t);
    }
}

// ---------------------------------------------------------------------------
// f32 -> bf16 bulk convert, 8 elems/thread
// ---------------------------------------------------------------------------
__global__ __launch_bounds__(256) void cvt_bf16(
    const float* __restrict__ src, unsigned short* __restrict__ dst)
{
    const long i = ((long)blockIdx.x * 256 + threadIdx.x) * 8;
    floatx4 v0 = *(const floatx4*)(src + i);
    floatx4 v1 = *(const floatx4*)(src + i + 4);
    short8 w;
#pragma unroll
    for (int j = 0; j < 4; ++j) w[j]     = (short)f32_to_bf16(v0[j]);
#pragma unroll
    for (int j = 0; j < 4; ++j) w[4 + j] = (short)f32_to_bf16(v1[j]);
    *(short8*)(dst + i) = w;
}

// ---------------------------------------------------------------------------
// g0[d] = sum_h bq[h] * Wk[d,h]   (Wk row-major (D,H)); one block per d
// ---------------------------------------------------------------------------
__global__ __launch_bounds__(256) void proj_bias(
    const float* __restrict__ bq, const float* __restrict__ Wk, float* __restrict__ g0)
{
    const int n = blockIdx.x;
    const int t = threadIdx.x;
    float s = 0.f;
    for (int h = t; h < DIM; h += 256) s += bq[h] * Wk[(long)n * DIM + h];
    for (int o = 32; o; o >>= 1) s += __shfl_xor(s, o);
    __shared__ float r[4];
    if ((t & 63) == 0) r[t >> 6] = s;
    __syncthreads();
    if (t == 0) g0[n] = r[0] + r[1] + r[2] + r[3];
}

// ---------------------------------------------------------------------------
// R0 kernel (proven): C = A @ B^T (+bias) * scale. 128x128 tile, BK=64,
// 256 threads (4 waves 2x2), 32x32x16 MFMA, XOR-swizzled single-buffer LDS.
// Kept for the small Gt GEMM only.
// ---------------------------------------------------------------------------
template<bool C_BF16, bool BIAS, bool LIMIT, bool SCATTER, int FLAT>
__global__ __launch_bounds__(256) void gemm_bt(
    const unsigned short* __restrict__ A, const unsigned short* __restrict__ Bt,
    void* __restrict__ Cp, const float* __restrict__ bias,
    int N, int K, long sA, long sB, long sC, float scale,
    const int* __restrict__ mlim, const int* __restrict__ cntp,
    const int* __restrict__ idx, int sh)
{
    int bx, by, bz;
    if (FLAT == 0) {
        bx = blockIdx.x; by = blockIdx.y; bz = blockIdx.z;
    } else {
        const int id = blockIdx.x;
        bz = id & 7;
        const int rem = id >> 3;
        const int m = (1 << sh) - 1;
        if (FLAT == 1) { bx = rem & m; by = rem >> sh; }
        else           { by = rem & m; bx = rem >> sh; }
    }
    const int row0 = bx * 128;
    if (LIMIT && row0 >= mlim[bz]) return;

    __shared__ unsigned short As[128 * 64];
    __shared__ unsigned short Bs[128 * 64];

    const int tid  = threadIdx.x;
    const int lane = tid & 63;
    const int wave = tid >> 6;
    const int wm   = wave >> 1;
    const int wn   = wave & 1;
    const int l31  = lane & 31;
    const int half = lane >> 5;
    const int x7   = lane & 7;
    const int col0 = by * 128;
    const long zA = (long)bz * sA;
    const long zB = (long)bz * sB;
    const long zC = (long)bz * sC;

    const int sr = lane >> 3;
    const int sq = ((lane & 7) ^ sr) * 8;

    const unsigned short* Abase = A  + zA + (long)row0 * K;
    const unsigned short* Bbase = Bt + zB + (long)col0 * K;
    const unsigned short* aptr[4];
    const unsigned short* bptr[4];
#pragma unroll
    for (int c = 0; c < 4; ++c) {
        const int r = (wave * 4 + c) * 8 + sr;
        aptr[c] = Abase + (long)r * K + sq;
        bptr[c] = Bbase + (long)r * K + sq;
    }

    floatx16 acc[2][2];
#pragma unroll
    for (int a = 0; a < 2; ++a)
#pragma unroll
        for (int b = 0; b < 2; ++b)
#pragma unroll
            for (int r = 0; r < 16; ++r) acc[a][b][r] = 0.f;

    const int raf[2] = { (wm * 64 +  0 + l31) * 64, (wm * 64 + 32 + l31) * 64 };
    const int rbf[2] = { (wn * 64 +  0 + l31) * 64, (wn * 64 + 32 + l31) * 64 };

    for (int kt = 0; kt < K; kt += 64) {
#pragma unroll
        for (int c = 0; c < 4; ++c) {
            const int chunk = wave * 4 + c;
            async_load16(aptr[c] + kt, As + chunk * 512);
            async_load16(bptr[c] + kt, Bs + chunk * 512);
        }
        __syncthreads();

#pragma unroll
        for (int ks = 0; ks < 4; ++ks) {
            const int sw = ((ks * 2 + half) ^ x7) << 3;
            short8 af[2], bf[2];
#pragma unroll
            for (int t = 0; t < 2; ++t) {
                af[t] = *(const short8*)(As + raf[t] + sw);
                bf[t] = *(const short8*)(Bs + rbf[t] + sw);
            }
#pragma unroll
            for (int tm = 0; tm < 2; ++tm)
#pragma unroll
                for (int tn = 0; tn < 2; ++tn)
                    acc[tm][tn] = __builtin_amdgcn_mfma_f32_32x32x16_bf16(
                        af[tm], bf[tn], acc[tm][tn], 0, 0, 0);
        }
        __syncthreads();
    }

    const int climit = SCATTER ? cntp[bz] : 0;
    const int* ridx  = SCATTER ? (idx + bz * SEQ) : (const int*)nullptr;
#pragma unroll
    for (int tn = 0; tn < 2; ++tn) {
        const int ccol = col0 + wn * 64 + tn * 32 + l31;
        float bv = 0.f;
        if (BIAS) bv = bias[ccol];
#pragma unroll
        for (int tm = 0; tm < 2; ++tm) {
            const int rbase = row0 + wm * 64 + tm * 32 + 4 * half;
#pragma unroll
            for (int r = 0; r < 16; ++r) {
                const int crow = rbase + (r & 3) + 8 * (r >> 2);
                float v = acc[tm][tn][r] * scale + bv;
                long orow = crow;
                if (SCATTER) {
                    if (crow >= climit) continue;
                    orow = ridx[crow];
                }
                const long ci = zC + orow * (long)N + ccol;
                if (C_BF16) ((unsigned short*)Cp)[ci] = f32_to_bf16(v);
                else        ((float*)Cp)[ci] = v;
            }
        }
    }
}

// ---------------------------------------------------------------------------
// R2: 256x256 8-phase GEMM (HK schedule, plain HIP).  C = A @ B^T.
// 512 threads = 8 waves (2M x 4N); per wave 128x64 via 16x16x32 MFMA.
// LDS 128KB dynamic: A,B each [dbuf=2][half=2][128x64] bf16; K-tile t -> slot
// t&1 (static).  Per K-tile 4 phases (one 64x32 C-quadrant each, 16 MFMA):
//   ph: { ds_read frags | stage 1 half-tile (2 x global_load_lds/wave) |
//         [lgkmcnt(8)] | barrier | lgkmcnt(0)+schedbar | setprio(1) 16 MFMA
//         setprio(0) | [vmcnt(4) at ph4/ph8] | barrier }
// Stage rotation (iter i, t=2i):  ph1:A0(t+1)s1  ph2:A1(t+1)s1  ph3:B0(t+2)s0
//   ph4:B1(t+2)s0  ph5:A0(t+2)s0  ph6:A1(t+2)s0  ph7:B0(t+3)s1  ph8:B1(t+3)s1
// vmcnt(4) at ph4/ph8 retires exactly the next K-tile's 4 halves, keeps 2
// stages (4 loads) in flight across barriers.  Last iter: stages ph1-2 only,
// vmcnt(0) at ph4.  Swizzle: LDS[r][slot] = glob[r][slot ^ (r&7)] (16B slots),
// read slot = (ks*4 + (lane>>4)) ^ (lane&7)  (involution, rule #21).
// ---------------------------------------------------------------------------
template<int D, int MQ>
__device__ __forceinline__ void read_a256(short8 (&af)[4][2],
                                          const unsigned short* const (&aB)[2][2]) {
#pragma unroll
    for (int mm = 0; mm < 4; ++mm)
#pragma unroll
        for (int ss = 0; ss < 2; ++ss)
            af[mm][ss] = *(const short8*)(aB[D][ss] + (MQ * 64 + mm * 16) * 64);
}

template<int D, int NQ>
__device__ __forceinline__ void read_b256(short8 (&bf)[2][2][2],
                                          const unsigned short* const (&bB)[2][2]) {
#pragma unroll
    for (int nn = 0; nn < 2; ++nn)
#pragma unroll
        for (int ss = 0; ss < 2; ++ss)
            bf[NQ][nn][ss] = *(const short8*)(bB[D][ss] + (NQ * 32 + nn * 16) * 64);
}

template<int MQ, int NQ>
__device__ __forceinline__ void mfma_q256(floatx4 (&acc)[8][4],
                                          const short8 (&af)[4][2],
                                          const short8 (&bf)[2][2][2]) {
    __builtin_amdgcn_s_setprio(1);
#pragma unroll
    for (int mm = 0; mm < 4; ++mm)
#pragma unroll
        for (int nn = 0; nn < 2; ++nn)
#pragma unroll
            for (int ss = 0; ss < 2; ++ss)
                acc[MQ * 4 + mm][NQ * 2 + nn] = __builtin_amdgcn_mfma_f32_16x16x32_bf16(
                    af[mm][ss], bf[NQ][nn][ss], acc[MQ * 4 + mm][NQ * 2 + nn], 0, 0, 0);
    __builtin_amdgcn_s_setprio(0);
}

__device__ __forceinline__ void stage2(const unsigned short* s0, const unsigned short* s1,
                                       unsigned short* d) {
    async_load16(s0, d);
    async_load16(s1, d + 512);
}

template<bool C_BF16, bool BIAS, bool LIMIT, bool SCATTER, int FLAT>
__global__ __launch_bounds__(512) void gemm256(
    const unsigned short* __restrict__ A, const unsigned short* __restrict__ Bt,
    void* __restrict__ Cp, const float* __restrict__ bias,
    int N, int K, long sA, long sB, long sC, float scale,
    const int* __restrict__ mlim, const int* __restrict__ cntp,
    const int* __restrict__ idx, int sh)
{
    extern __shared__ unsigned short smem[];    // 128KB
    unsigned short* AsP = smem;                  // [2][2][8192] shorts
    unsigned short* BsP = smem + 32768;

    int bx, by, bz;
    if (FLAT == 0) {
        bx = blockIdx.x; by = blockIdx.y; bz = blockIdx.z;
    } else {
        const int id = blockIdx.x;
        bz = id & 7;
        const int rem = id >> 3;
        const int m = (1 << sh) - 1;
        if (FLAT == 1) { bx = rem & m; by = rem >> sh; }
        else           { by = rem & m; bx = rem >> sh; }
    }
    const int row0 = bx * 256;
    if (LIMIT && row0 >= mlim[bz]) return;
    const int col0 = by * 256;

    const int tid  = threadIdx.x;
    const int lane = tid & 63;
    const int wave = tid >> 6;       // 0..7
    const int wm   = wave >> 2;      // 0..1
    const int wn   = wave & 3;       // 0..3
    const int l15  = lane & 15;
    const int kg   = lane >> 4;      // 0..3
    const int l7   = lane & 7;
    const long zA = (long)bz * sA;
    const long zB = (long)bz * sB;
    const long zC = (long)bz * sC;

    // staging source: chunk = 8 rows x 64 shorts; lane -> row sr=lane>>3,
    // global 16B-slot = (lane&7) ^ sr   (LDS dest linear)
    const int sr = lane >> 3;
    const int sq = ((lane & 7) ^ sr) * 8;
    const unsigned short* Abase = A  + zA + (long)row0 * K;
    const unsigned short* Bbase = Bt + zB + (long)col0 * K;
    const unsigned short* aSrc[2][2];   // [half][chunk]
    const unsigned short* bSrc[2][2];
#pragma unroll
    for (int h = 0; h < 2; ++h)
#pragma unroll
        for (int cc = 0; cc < 2; ++cc) {
            const long r = h * 128 + wave * 16 + cc * 8 + sr;
            aSrc[h][cc] = Abase + r * K + sq;
            bSrc[h][cc] = Bbase + r * K + sq;
        }

    // frag read bases: [dbuf][ksub]; read slot = (ss*4+kg)^l7  (16B units)
    const int sOff0 = ((0 * 4 + kg) ^ l7) * 8;
    const int sOff1 = ((1 * 4 + kg) ^ l7) * 8;
    const unsigned short* aB[2][2];
    const unsigned short* bB[2][2];
#pragma unroll
    for (int d = 0; d < 2; ++d) {
        aB[d][0] = AsP + (d * 2 + wm) * 8192 + l15 * 64 + sOff0;
        aB[d][1] = AsP + (d * 2 + wm) * 8192 + l15 * 64 + sOff1;
        bB[d][0] = BsP + (d * 2 + (wn >> 1)) * 8192 + ((wn & 1) * 64 + l15) * 64 + sOff0;
        bB[d][1] = BsP + (d * 2 + (wn >> 1)) * 8192 + ((wn & 1) * 64 + l15) * 64 + sOff1;
    }

    floatx4 acc[8][4];
#pragma unroll
    for (int mm = 0; mm < 8; ++mm)
#pragma unroll
        for (int nn = 0; nn < 4; ++nn)
#pragma unroll
            for (int r = 0; r < 4; ++r) acc[mm][nn][r] = 0.f;

    short8 af[4][2];
    short8 bf[2][2][2];

#define ST_A(DD, HH, KT) stage2(aSrc[HH][0] + (KT), aSrc[HH][1] + (KT), \
                                AsP + ((DD) * 2 + (HH)) * 8192 + wave * 1024)
#define ST_B(DD, HH, KT) stage2(bSrc[HH][0] + (KT), bSrc[HH][1] + (KT), \
                                BsP + ((DD) * 2 + (HH)) * 8192 + wave * 1024)

    const int NI = K >> 7;           // iterations of 2 K-tiles

    // prologue: B0(0) B1(0) A0(0) A1(0) -> slot0; B0(1) B1(1) -> slot1
    ST_B(0, 0, 0);  ST_B(0, 1, 0);
    ST_A(0, 0, 0);  ST_A(0, 1, 0);
    ST_B(1, 0, 64); ST_B(1, 1, 64);
    asm volatile("s_waitcnt vmcnt(4)" ::: "memory");   // tile0 landed, 2 stages in flight
    __builtin_amdgcn_sched_barrier(0);
    BARF();

#pragma unroll 1
    for (int i = 0; i < NI; ++i) {
        const bool nl = (i < NI - 1);
        const long kA = (long)(2 * i + 1) * 64;
        const long kB = (long)(2 * i + 2) * 64;
        const long kC = (long)(2 * i + 3) * 64;

        // ---- ph1: K-tile t (slot0), quadrant (0,0); 12 reads ----
        read_a256<0, 0>(af, aB);
        read_b256<0, 0>(bf, bB);
        ST_A(1, 0, kA);
        asm volatile("s_waitcnt lgkmcnt(8)" ::: "memory");
        BARF();
        WAIT_LGKM0;
        mfma_q256<0, 0>(acc, af, bf);
        BARF();
        // ---- ph2: quadrant (0,1); 4 reads ----
        read_b256<0, 1>(bf, bB);
        ST_A(1, 1, kA);
        BARF();
        WAIT_LGKM0;
        mfma_q256<0, 1>(acc, af, bf);
        BARF();
        // ---- ph3: quadrant (1,1); 8 reads ----
        read_a256<0, 1>(af, aB);
        if (nl) ST_B(0, 0, kB);
        BARF();
        WAIT_LGKM0;
        mfma_q256<1, 1>(acc, af, bf);
        BARF();
        // ---- ph4: quadrant (1,0); 0 reads; vmcnt ----
        if (nl) ST_B(0, 1, kB);
        BARF();
        mfma_q256<1, 0>(acc, af, bf);
        if (nl) { asm volatile("s_waitcnt vmcnt(4)" ::: "memory"); }
        else    { asm volatile("s_waitcnt vmcnt(0)" ::: "memory"); }
        __builtin_amdgcn_sched_barrier(0);
        BARF();
        // ---- ph5: K-tile t+1 (slot1), quadrant (0,0); 12 reads ----
        read_a256<1, 0>(af, aB);
        read_b256<1, 0>(bf, bB);
        if (nl) ST_A(0, 0, kB);
        asm volatile("s_waitcnt lgkmcnt(8)" ::: "memory");
        BARF();
        WAIT_LGKM0;
        mfma_q256<0, 0>(acc, af, bf);
        BARF();
        // ---- ph6: quadrant (0,1) ----
        read_b256<1, 1>(bf, bB);
        if (nl) ST_A(0, 1, kB);
        BARF();
        WAIT_LGKM0;
        mfma_q256<0, 1>(acc, af, bf);
        BARF();
        // ---- ph7: quadrant (1,1) ----
        read_a256<1, 1>(af, aB);
        if (nl) ST_B(1, 0, kC);
        BARF();
        WAIT_LGKM0;
        mfma_q256<1, 1>(acc, af, bf);
        BARF();
        // ---- ph8: quadrant (1,0); vmcnt ----
        if (nl) ST_B(1, 1, kC);
        BARF();
        mfma_q256<1, 0>(acc, af, bf);
        if (nl) {
            asm volatile("s_waitcnt vmcnt(4)" ::: "memory");
            __builtin_amdgcn_sched_barrier(0);
            BARF();
        }
    }
#undef ST_A
#undef ST_B

    // epilogue: 16x16 C/D layout col=lane&15, row=(lane>>4)*4+reg
    const int climit = SCATTER ? cntp[bz] : 0;
    const int* ridx  = SCATTER ? (idx + bz * SEQ) : (const int*)nullptr;
#pragma unroll
    for (int nn = 0; nn < 4; ++nn) {
        const int ccol = col0 + wn * 64 + nn * 16 + l15;
        float bv = 0.f;
        if (BIAS) bv = bias[ccol];
#pragma unroll
        for (int mm = 0; mm < 8; ++mm) {
            const int rb = row0 + wm * 128 + mm * 16 + kg * 4;
#pragma unroll
            for (int r = 0; r < 4; ++r) {
                const int crow = rb + r;
                float v = acc[mm][nn][r] * scale + bv;
                long orow = crow;
                if (SCATTER) {
                    if (crow >= climit) continue;
                    orow = ridx[crow];
                }
                const long ci = zC + orow * (long)N + ccol;
                if (C_BF16) ((unsigned short*)Cp)[ci] = f32_to_bf16(v);
                else        ((float*)Cp)[ci] = v;
            }
        }
    }
}

// ---------------------------------------------------------------------------
// in-place row softmax over 2048 bf16 scores; one block per compacted row
// ---------------------------------------------------------------------------
__global__ __launch_bounds__(256) void softmax_rows(
    unsigned short* __restrict__ S, const int* __restrict__ padcnt)
{
    const int b = blockIdx.x >> 11, rc = blockIdx.x & 2047;
    if (rc >= padcnt[b]) return;
    const long base = (long)blockIdx.x * SEQ + threadIdx.x * 8;
    const int lane = threadIdx.x & 63, wave = threadIdx.x >> 6;
    __shared__ float rbuf[8];

    short8 v = *(const short8*)(S + base);
    float x[8];
#pragma unroll
    for (int j = 0; j < 8; ++j) x[j] = bf16_to_f32((unsigned short)v[j]);

    float m = x[0];
#pragma unroll
    for (int j = 1; j < 8; ++j) m = fmaxf(m, x[j]);
    for (int o = 32; o; o >>= 1) m = fmaxf(m, __shfl_xor(m, o));
    if (lane == 0) rbuf[wave] = m;
    __syncthreads();
    m = fmaxf(fmaxf(rbuf[0], rbuf[1]), fmaxf(rbuf[2], rbuf[3]));

    float e[8], s = 0.f;
#pragma unroll
    for (int j = 0; j < 8; ++j) { e[j] = __expf(x[j] - m); s += e[j]; }
    for (int o = 32; o; o >>= 1) s += __shfl_xor(s, o);
    if (lane == 0) rbuf[4 + wave] = s;
    __syncthreads();
    s = rbuf[4] + rbuf[5] + rbuf[6] + rbuf[7];
    const float inv = 1.0f / s;

    short8 o8;
#pragma unroll
    for (int j = 0; j < 8; ++j) o8[j] = (short)f32_to_bf16(e[j] * inv);
    *(short8*)(S + base) = o8;
}

// ---------------------------------------------------------------------------
// rows with mask<=0.5: out[b,i,:] = mavg[b,:]/masked_count  (exact fp32 path)
// ---------------------------------------------------------------------------
__global__ __launch_bounds__(256) void overwrite_masked(
    float* __restrict__ out, const float* __restrict__ mask,
    const float* __restrict__ mavg, const int* __restrict__ cnt)
{
    const int bid = blockIdx.x;            // b*SEQ + i
    const int b = bid >> 11;
    if (mask[bid] > 0.5f) return;
    const float inv = 1.0f / (float)(SEQ - cnt[b]);
    const long obase = (long)bid * DIM;
    const float* mv = mavg + b * DIM;
    for (int d = threadIdx.x; d < DIM; d += 256)
        out[obase + d] = mv[d] * inv;
}

extern "C" void kernel_launch(void* const* d_in, const int* in_sizes, int n_in,
                              void* d_out, int out_size, void* d_ws, size_t ws_size,
                              hipStream_t stream) {
    (void)in_sizes; (void)n_in; (void)out_size;
    const float* input_q = (const float*)d_in[0];
    const float* input_k = (const float*)d_in[1];
    const float* k_mask  = (const float*)d_in[2];
    const float* Wq      = (const float*)d_in[3];
    const float* bq      = (const float*)d_in[4];
    const float* Wk      = (const float*)d_in[5];
    const float* bk      = (const float*)d_in[6];
    (void)bk;   // bk shifts each score row by a constant -> softmax-invariant
    float* out = (float*)d_out;

    // Workspace map (aliases sequenced by stream order):
    //   qc   aliases S lo 32MB      (dead once qpp computed, before scores writes S)
    //   Wqb/Wkb alias qpp lo 4MB    (dead once Gt computed, before qpp written)
    char* ws = (char*)d_ws;
    unsigned short* qc   = (unsigned short*)(ws);                 // 32MB
    unsigned short* S    = (unsigned short*)(ws);                 // 64MB
    unsigned short* qpp  = (unsigned short*)(ws + 67108864);      // 32MB
    unsigned short* Wqb  = (unsigned short*)(ws + 67108864);      // 2MB (alias)
    unsigned short* Wkb  = (unsigned short*)(ws + 69206016);      // 2MB (alias)
    unsigned short* kbf  = (unsigned short*)(ws + 100663296);     // 32MB
    unsigned short* Vt   = (unsigned short*)(ws + 134217728);     // 32MB
    unsigned short* Gt   = (unsigned short*)(ws + 167772160);     // 2MB
    float*          g0   = (float*)(ws + 169869312);              // 4KB
    float*          mavg = (float*)(ws + 169873408);              // 32KB
    int*            idx  = (int*)(ws + 169906176);                // 64KB
    int*            cnts = (int*)(ws + 169971712);                // 32B
    int*            pcnt = (int*)(ws + 169971744);                // 32B
    if (ws_size < 169971776) return;

    // allow 128KB dynamic LDS for the 8-phase GEMM instantiations (idempotent)
    static bool attr_set = false;
    if (!attr_set) {
        hipFuncSetAttribute((const void*)gemm256<true, true, true, false, 2>,
                            hipFuncAttributeMaxDynamicSharedMemorySize, 131072);
        hipFuncSetAttribute((const void*)gemm256<true, false, true, false, 1>,
                            hipFuncAttributeMaxDynamicSharedMemorySize, 131072);
        hipFuncSetAttribute((const void*)gemm256<false, false, true, true, 2>,
                            hipFuncAttributeMaxDynamicSharedMemorySize, 131072);
        attr_set = true;
    }

    hipMemsetAsync(mavg, 0, BATCH * DIM * sizeof(float), stream);

    build_idx<<<BATCH, 256, 0, stream>>>(k_mask, idx, cnts, pcnt);
    gather_cvt_q<<<dim3(SEQ, BATCH), 256, 0, stream>>>(input_q, idx, pcnt, qc);
    prep_kv<<<dim3(DIM / 32, SEQ / 32, BATCH), 256, 0, stream>>>(input_k, k_mask, kbf, Vt, mavg);
    cvt_bf16<<<512, 256, 0, stream>>>(Wq, Wqb);
    cvt_bf16<<<512, 256, 0, stream>>>(Wk, Wkb);
    proj_bias<<<DIM, 256, 0, stream>>>(bq, Wk, g0);

    // Gt[d,e] = sum_h Wk[d,h] * Wq[e,h]   (combined projection, 1024^3)
    gemm_bt<true, false, false, false, 0><<<dim3(8, 8, 1), 256, 0, stream>>>(
        Wkb, Wqb, Gt, nullptr, DIM, DIM, 0, 0, 0, 1.0f, nullptr, nullptr, nullptr, 0);

    // q''[m,d] = sum_e qc[m,e] * Gt[d,e] + g0[d]  (256^2 8-phase; batch->XCD, y-fast ny=4)
    gemm256<true, true, true, false, 2><<<8 * 8 * 4, 512, 131072, stream>>>(
        qc, Gt, qpp, g0, DIM, DIM,
        (long)SEQ * DIM, 0, (long)SEQ * DIM, 1.0f, pcnt, nullptr, nullptr, 2);

    // scores: S[i,j] = q''[i,:] . kbf[j,:] / 32 -> bf16  (256^2 8-phase; x-fast nx=8)
    gemm256<true, false, true, false, 1><<<8 * 8 * 8, 512, 131072, stream>>>(
        qpp, kbf, S, nullptr, SEQ, DIM,
        (long)SEQ * DIM, (long)SEQ * DIM, (long)SEQ * SEQ, 0.03125f, pcnt, nullptr, nullptr, 3);

    softmax_rows<<<BATCH * SEQ, 256, 0, stream>>>(S, pcnt);

    // out rows (scattered): per batch P @ V  (256^2 8-phase; y-fast ny=4)
    gemm256<false, false, true, true, 2><<<8 * 8 * 4, 512, 131072, stream>>>(
        S, Vt, out, nullptr, DIM, SEQ,
        (long)SEQ * SEQ, (long)DIM * SEQ, (long)SEQ * DIM, 1.0f, pcnt, cnts, idx, 2);

    overwrite_masked<<<BATCH * SEQ, 256, 0, stream>>>(out, k_mask, mavg, cnts);
}

// Round 3
// 371.001 us; speedup vs baseline: 1.0829x; 1.0829x over previous
//
#include <hip/hip_runtime.h>

#define BATCH 8
#define SEQ   2048
#define DIM   1024   // D == H == 1024

typedef __attribute__((ext_vector_type(8)))  short short8;
typedef __attribute__((ext_vector_type(4)))  short short4v;
typedef __attribute__((ext_vector_type(4)))  float floatx4;
typedef __attribute__((ext_vector_type(16))) float floatx16;

__device__ __forceinline__ unsigned short f32_to_bf16(float f) {
    union { float f; unsigned int u; } x; x.f = f;
    unsigned int r = x.u + 0x7fffu + ((x.u >> 16) & 1u);
    return (unsigned short)(r >> 16);
}

__device__ __forceinline__ float bf16_to_f32(unsigned short h) {
    union { unsigned int u; float f; } x; x.u = ((unsigned int)h) << 16;
    return x.f;
}

// async 16B/lane global->LDS. LDS base wave-uniform; HW scatters lane i at base+16*i.
__device__ __forceinline__ void async_load16(const void* g, void* l) {
    __builtin_amdgcn_global_load_lds(
        (const __attribute__((address_space(1))) void*)g,
        (__attribute__((address_space(3))) void*)l, 16, 0, 0);
}

// ---------------------------------------------------------------------------
// per-batch compaction: idx[b][0..cnt) = rows with mask>0.5 (ascending),
// pads idx[cnt..SEQ) = 0; cnt[b]; padcnt[b] = round-up-128(cnt).
// ---------------------------------------------------------------------------
__global__ __launch_bounds__(256) void build_idx(
    const float* __restrict__ mask, int* __restrict__ idx,
    int* __restrict__ cnt, int* __restrict__ padcnt)
{
    const int b = blockIdx.x;
    const int t = threadIdx.x;
    const float* mb = mask + b * SEQ;
    int flags[8]; int c = 0;
#pragma unroll
    for (int j = 0; j < 8; ++j) {
        flags[j] = (mb[t * 8 + j] > 0.5f) ? 1 : 0;
        c += flags[j];
    }
    int sc = c;                       // inclusive scan within wave
    for (int o = 1; o < 64; o <<= 1) {
        int v = __shfl_up(sc, o);
        if ((t & 63) >= o) sc += v;
    }
    __shared__ int wtot[4];
    const int lane = t & 63, wave = t >> 6;
    if (lane == 63) wtot[wave] = sc;
    __syncthreads();
    int woff = 0;
    for (int w = 0; w < wave; ++w) woff += wtot[w];
    int p = woff + sc - c;            // exclusive offset
#pragma unroll
    for (int j = 0; j < 8; ++j)
        if (flags[j]) idx[b * SEQ + (p++)] = t * 8 + j;
    __syncthreads();
    const int total = wtot[0] + wtot[1] + wtot[2] + wtot[3];
    if (t == 0) { cnt[b] = total; padcnt[b] = (total + 127) & ~127; }
    for (int q = total + t; q < SEQ; q += 256) idx[b * SEQ + q] = 0;
}

// ---------------------------------------------------------------------------
// gather unmasked input_q rows (f32) -> compacted bf16 rows
// ---------------------------------------------------------------------------
__global__ __launch_bounds__(256) void gather_cvt_q(
    const float* __restrict__ xq, const int* __restrict__ idx,
    const int* __restrict__ padcnt, unsigned short* __restrict__ qc)
{
    const int b = blockIdx.y;
    const int rc = blockIdx.x;
    if (rc >= padcnt[b]) return;
    const int src = idx[b * SEQ + rc];
    const float* s = xq + ((long)b * SEQ + src) * DIM + threadIdx.x * 4;
    unsigned short* d = qc + ((long)b * SEQ + rc) * DIM + threadIdx.x * 4;
    floatx4 v = *(const floatx4*)s;
    short4v w;
#pragma unroll
    for (int j = 0; j < 4; ++j) w[j] = (short)f32_to_bf16(v[j]);
    *(short4v*)d = w;
}

// ---------------------------------------------------------------------------
// fused single pass over input_k:
//   kbf = bf16(input_k)  (straight layout)
//   Vt  = bf16(input_k)^T per batch (DIM x SEQ)
//   mavg += masked column partial sums
// grid (DIM/32, SEQ/32, BATCH), block 256 (32x8)
// ---------------------------------------------------------------------------
__global__ __launch_bounds__(256) void prep_kv(
    const float* __restrict__ xk, const float* __restrict__ mask,
    unsigned short* __restrict__ kbf, unsigned short* __restrict__ Vt,
    float* __restrict__ mavg)
{
    __shared__ float tile[32][33];
    __shared__ float msk[32];
    __shared__ float csum[8][32];
    const int b  = blockIdx.z;
    const int c0 = blockIdx.x * 32;   // dim cols
    const int r0 = blockIdx.y * 32;   // seq rows
    const int tx = threadIdx.x & 31, ty = threadIdx.x >> 5;   // ty 0..7
    const float* xb = xk + (long)b * SEQ * DIM;
    unsigned short* kb = kbf + (long)b * SEQ * DIM;
    unsigned short* vb = Vt + (long)b * DIM * SEQ;

    if (threadIdx.x < 32) msk[threadIdx.x] = mask[b * SEQ + r0 + threadIdx.x];

    float v[4];
#pragma unroll
    for (int i = 0; i < 4; ++i) {
        const int r = ty + i * 8;
        v[i] = xb[(long)(r0 + r) * DIM + c0 + tx];
        tile[r][tx] = v[i];
        kb[(long)(r0 + r) * DIM + c0 + tx] = f32_to_bf16(v[i]);
    }
    __syncthreads();

    float s = 0.f;
#pragma unroll
    for (int i = 0; i < 4; ++i) {
        const int r = ty + i * 8;
        s += (msk[r] <= 0.5f) ? v[i] : 0.f;
    }
    csum[ty][tx] = s;

#pragma unroll
    for (int i = 0; i < 4; ++i) {
        const int c = ty + i * 8;
        vb[(long)(c0 + c) * SEQ + r0 + tx] = f32_to_bf16(tile[tx][c]);
    }
    __syncthreads();
    if (ty == 0) {
        float t = 0.f;
#pragma unroll
        for (int j = 0; j < 8; ++j) t += csum[j][tx];
        atomicAdd(&mavg[b * DIM + c0 + tx], t);
    }
}

// ---------------------------------------------------------------------------
// f32 -> bf16 bulk convert of BOTH weight matrices in one launch.
// blocks [0,512): Wq -> Wqb ; blocks [512,1024): Wk -> Wkb. 8 elems/thread.
// ---------------------------------------------------------------------------
__global__ __launch_bounds__(256) void cvt_bf16_2(
    const float* __restrict__ s0, unsigned short* __restrict__ d0,
    const float* __restrict__ s1, unsigned short* __restrict__ d1)
{
    const int hi = blockIdx.x >> 9;
    const float* src = hi ? s1 : s0;
    unsigned short* dst = hi ? d1 : d0;
    const long i = ((long)(blockIdx.x & 511) * 256 + threadIdx.x) * 8;
    floatx4 v0 = *(const floatx4*)(src + i);
    floatx4 v1 = *(const floatx4*)(src + i + 4);
    short8 w;
#pragma unroll
    for (int j = 0; j < 4; ++j) w[j]     = (short)f32_to_bf16(v0[j]);
#pragma unroll
    for (int j = 0; j < 4; ++j) w[4 + j] = (short)f32_to_bf16(v1[j]);
    *(short8*)(dst + i) = w;
}

// ---------------------------------------------------------------------------
// g0[d] = sum_h bq[h] * Wk[d,h]   (Wk row-major (D,H)); one block per d
// ---------------------------------------------------------------------------
__global__ __launch_bounds__(256) void proj_bias(
    const float* __restrict__ bq, const float* __restrict__ Wk, float* __restrict__ g0)
{
    const int n = blockIdx.x;
    const int t = threadIdx.x;
    float s = 0.f;
    for (int h = t; h < DIM; h += 256) s += bq[h] * Wk[(long)n * DIM + h];
    for (int o = 32; o; o >>= 1) s += __shfl_xor(s, o);
    __shared__ float r[4];
    if ((t & 63) == 0) r[t >> 6] = s;
    __syncthreads();
    if (t == 0) g0[n] = r[0] + r[1] + r[2] + r[3];
}

// ---------------------------------------------------------------------------
// C = A @ B^T (+bias) * scale.  A: MxK bf16, Bt: NxK bf16, C: MxN (bf16|f32).
// 128x128 block tile, BK=64, 256 threads (4 waves 2x2), each wave 64x64 via
// 2x2 v_mfma_f32_32x32x16_bf16.  XOR-swizzled LDS staging, single buffer.
//
// R3: occupancy squeeze.  acc = 64 AGPR; total regs must be <=128 for
// 4 waves/SIMD (occupancy steps at 64/128/256 — m69).  The old aptr[4]/
// bptr[4] arrays held 16 VGPRs of loop-invariant pointers; replaced by
// aRow/bRow base + uniform c*(8K) addend (SALU).  __launch_bounds__(256,4)
// pins 4 waves/EU -> 4 blocks/CU (LDS 32KB allows 5).
//
// FLAT grid modes (XCD locality): 0 = normal 3D grid.
//   1 = flat 1D, batch = id&7 (pins batch->XCD), x = rem & ((1<<sh)-1), y = rem>>sh
//   2 = flat 1D, batch = id&7, y = rem & ((1<<sh)-1), x = rem>>sh
// LIMIT: skip row-blocks past mlim[z].  SCATTER: row -> idx[z][row], < cnt[z].
// ---------------------------------------------------------------------------
template<bool C_BF16, bool BIAS, bool LIMIT, bool SCATTER, int FLAT>
__global__ __launch_bounds__(256, 4) void gemm_bt(
    const unsigned short* __restrict__ A, const unsigned short* __restrict__ Bt,
    void* __restrict__ Cp, const float* __restrict__ bias,
    int N, int K, long sA, long sB, long sC, float scale,
    const int* __restrict__ mlim, const int* __restrict__ cntp,
    const int* __restrict__ idx, int sh)
{
    int bx, by, bz;
    if (FLAT == 0) {
        bx = blockIdx.x; by = blockIdx.y; bz = blockIdx.z;
    } else {
        const int id = blockIdx.x;
        bz = id & 7;                       // batch -> XCD (round-robin heuristic)
        const int rem = id >> 3;
        const int m = (1 << sh) - 1;
        if (FLAT == 1) { bx = rem & m; by = rem >> sh; }
        else           { by = rem & m; bx = rem >> sh; }
    }
    const int row0 = bx * 128;
    if (LIMIT && row0 >= mlim[bz]) return;

    __shared__ unsigned short As[128 * 64];
    __shared__ unsigned short Bs[128 * 64];

    const int tid  = threadIdx.x;
    const int lane = tid & 63;
    const int wave = tid >> 6;
    const int wm   = wave >> 1;       // 0..1
    const int wn   = wave & 1;        // 0..1
    const int l31  = lane & 31;
    const int half = lane >> 5;       // 0..1
    const int x7   = lane & 7;
    const int col0 = by * 128;

    // staging: one async chunk = 1KB = 8 rows x 128B. lane i -> row sr=i>>3,
    // LDS slot i&7; global k-chunk sq = (i&7)^sr (XOR swizzle, in shorts*8)
    const int sr = lane >> 3;                  // 0..7
    const int sq = ((lane & 7) ^ sr) * 8;      // shorts

    const long K8 = (long)K * 8;               // 8-row stride in shorts (uniform)
    const unsigned short* aRow =
        A + (long)bz * sA + (long)row0 * K + (long)(wave * 32 + sr) * K + sq;
    const unsigned short* bRow =
        Bt + (long)bz * sB + (long)col0 * K + (long)(wave * 32 + sr) * K + sq;

    floatx16 acc[2][2];
#pragma unroll
    for (int a = 0; a < 2; ++a)
#pragma unroll
        for (int b = 0; b < 2; ++b)
#pragma unroll
            for (int r = 0; r < 16; ++r) acc[a][b][r] = 0.f;

    // fragment row bases (shorts): row stride 64
    const int raf[2] = { (wm * 64 +  0 + l31) * 64, (wm * 64 + 32 + l31) * 64 };
    const int rbf[2] = { (wn * 64 +  0 + l31) * 64, (wn * 64 + 32 + l31) * 64 };

    for (int kt = 0; kt < K; kt += 64) {
#pragma unroll
        for (int c = 0; c < 4; ++c) {
            const int chunk = wave * 4 + c;
            async_load16(aRow + kt + c * K8, As + chunk * 512);
            async_load16(bRow + kt + c * K8, Bs + chunk * 512);
        }
        __syncthreads();

#pragma unroll
        for (int ks = 0; ks < 4; ++ks) {
            const int sw = ((ks * 2 + half) ^ x7) << 3;   // swizzled 16B slot (shorts)
            short8 af[2], bf[2];
#pragma unroll
            for (int t = 0; t < 2; ++t) {
                af[t] = *(const short8*)(As + raf[t] + sw);
                bf[t] = *(const short8*)(Bs + rbf[t] + sw);
            }
#pragma unroll
            for (int tm = 0; tm < 2; ++tm)
#pragma unroll
                for (int tn = 0; tn < 2; ++tn)
                    acc[tm][tn] = __builtin_amdgcn_mfma_f32_32x32x16_bf16(
                        af[tm], bf[tn], acc[tm][tn], 0, 0, 0);
        }
        __syncthreads();
    }

    // epilogue: 32x32 C/D layout col=lane&31, row=(reg&3)+8*(reg>>2)+4*(lane>>5)
    const long zC = (long)bz * sC;
    const int climit = SCATTER ? cntp[bz] : 0;
    const int* ridx  = SCATTER ? (idx + bz * SEQ) : (const int*)nullptr;
#pragma unroll
    for (int tn = 0; tn < 2; ++tn) {
        const int ccol = col0 + wn * 64 + tn * 32 + l31;
        float bv = 0.f;
        if (BIAS) bv = bias[ccol];
#pragma unroll
        for (int tm = 0; tm < 2; ++tm) {
            const int rbase = row0 + wm * 64 + tm * 32 + 4 * half;
#pragma unroll
            for (int r = 0; r < 16; ++r) {
                const int crow = rbase + (r & 3) + 8 * (r >> 2);
                float v = acc[tm][tn][r] * scale + bv;
                long orow = crow;
                if (SCATTER) {
                    if (crow >= climit) continue;
                    orow = ridx[crow];
                }
                const long ci = zC + orow * (long)N + ccol;
                if (C_BF16) ((unsigned short*)Cp)[ci] = f32_to_bf16(v);
                else        ((float*)Cp)[ci] = v;
            }
        }
    }
}

// ---------------------------------------------------------------------------
// in-place row softmax over 2048 bf16 scores; one block per compacted row
// ---------------------------------------------------------------------------
__global__ __launch_bounds__(256) void softmax_rows(
    unsigned short* __restrict__ S, const int* __restrict__ padcnt)
{
    const int b = blockIdx.x >> 11, rc = blockIdx.x & 2047;
    if (rc >= padcnt[b]) return;
    const long base = (long)blockIdx.x * SEQ + threadIdx.x * 8;
    const int lane = threadIdx.x & 63, wave = threadIdx.x >> 6;
    __shared__ float rbuf[8];

    short8 v = *(const short8*)(S + base);
    float x[8];
#pragma unroll
    for (int j = 0; j < 8; ++j) x[j] = bf16_to_f32((unsigned short)v[j]);

    float m = x[0];
#pragma unroll
    for (int j = 1; j < 8; ++j) m = fmaxf(m, x[j]);
    for (int o = 32; o; o >>= 1) m = fmaxf(m, __shfl_xor(m, o));
    if (lane == 0) rbuf[wave] = m;
    __syncthreads();
    m = fmaxf(fmaxf(rbuf[0], rbuf[1]), fmaxf(rbuf[2], rbuf[3]));

    float e[8], s = 0.f;
#pragma unroll
    for (int j = 0; j < 8; ++j) { e[j] = __expf(x[j] - m); s += e[j]; }
    for (int o = 32; o; o >>= 1) s += __shfl_xor(s, o);
    if (lane == 0) rbuf[4 + wave] = s;
    __syncthreads();
    s = rbuf[4] + rbuf[5] + rbuf[6] + rbuf[7];
    const float inv = 1.0f / s;

    short8 o8;
#pragma unroll
    for (int j = 0; j < 8; ++j) o8[j] = (short)f32_to_bf16(e[j] * inv);
    *(short8*)(S + base) = o8;
}

// ---------------------------------------------------------------------------
// rows with mask<=0.5: out[b,i,:] = mavg[b,:]/masked_count  (exact fp32 path)
// ---------------------------------------------------------------------------
__global__ __launch_bounds__(256) void overwrite_masked(
    float* __restrict__ out, const float* __restrict__ mask,
    const float* __restrict__ mavg, const int* __restrict__ cnt)
{
    const int bid = blockIdx.x;            // b*SEQ + i
    const int b = bid >> 11;
    if (mask[bid] > 0.5f) return;
    const float inv = 1.0f / (float)(SEQ - cnt[b]);
    const long obase = (long)bid * DIM;
    const float* mv = mavg + b * DIM;
    for (int d = threadIdx.x; d < DIM; d += 256)
        out[obase + d] = mv[d] * inv;
}

extern "C" void kernel_launch(void* const* d_in, const int* in_sizes, int n_in,
                              void* d_out, int out_size, void* d_ws, size_t ws_size,
                              hipStream_t stream) {
    (void)in_sizes; (void)n_in; (void)out_size;
    const float* input_q = (const float*)d_in[0];
    const float* input_k = (const float*)d_in[1];
    const float* k_mask  = (const float*)d_in[2];
    const float* Wq      = (const float*)d_in[3];
    const float* bq      = (const float*)d_in[4];
    const float* Wk      = (const float*)d_in[5];
    const float* bk      = (const float*)d_in[6];
    (void)bk;   // bk shifts each score row by a constant -> softmax-invariant
    float* out = (float*)d_out;

    // Workspace map (aliases sequenced by stream order):
    //   qc   aliases S lo 32MB      (dead once qpp computed, before scores writes S)
    //   Wqb/Wkb alias qpp lo 4MB    (dead once Gt computed, before qpp written)
    char* ws = (char*)d_ws;
    unsigned short* qc   = (unsigned short*)(ws);                 // 32MB
    unsigned short* S    = (unsigned short*)(ws);                 // 64MB
    unsigned short* qpp  = (unsigned short*)(ws + 67108864);      // 32MB
    unsigned short* Wqb  = (unsigned short*)(ws + 67108864);      // 2MB (alias)
    unsigned short* Wkb  = (unsigned short*)(ws + 69206016);      // 2MB (alias)
    unsigned short* kbf  = (unsigned short*)(ws + 100663296);     // 32MB
    unsigned short* Vt   = (unsigned short*)(ws + 134217728);     // 32MB
    unsigned short* Gt   = (unsigned short*)(ws + 167772160);     // 2MB
    float*          g0   = (float*)(ws + 169869312);              // 4KB
    float*          mavg = (float*)(ws + 169873408);              // 32KB
    int*            idx  = (int*)(ws + 169906176);                // 64KB
    int*            cnts = (int*)(ws + 169971712);                // 32B
    int*            pcnt = (int*)(ws + 169971744);                // 32B
    if (ws_size < 169971776) return;

    hipMemsetAsync(mavg, 0, BATCH * DIM * sizeof(float), stream);

    build_idx<<<BATCH, 256, 0, stream>>>(k_mask, idx, cnts, pcnt);
    gather_cvt_q<<<dim3(SEQ, BATCH), 256, 0, stream>>>(input_q, idx, pcnt, qc);
    prep_kv<<<dim3(DIM / 32, SEQ / 32, BATCH), 256, 0, stream>>>(input_k, k_mask, kbf, Vt, mavg);
    cvt_bf16_2<<<1024, 256, 0, stream>>>(Wq, Wqb, Wk, Wkb);
    proj_bias<<<DIM, 256, 0, stream>>>(bq, Wk, g0);

    // Gt[d,e] = sum_h Wk[d,h] * Wq[e,h]   (combined projection, 1024^3)
    gemm_bt<true, false, false, false, 0><<<dim3(8, 8, 1), 256, 0, stream>>>(
        Wkb, Wqb, Gt, nullptr, DIM, DIM, 0, 0, 0, 1.0f, nullptr, nullptr, nullptr, 0);

    // q''[m,d] = sum_e qc[m,e] * Gt[d,e] + g0[d]   (compacted; batch->XCD, y-fast ny=8)
    gemm_bt<true, true, true, false, 2><<<8 * 16 * 8, 256, 0, stream>>>(
        qc, Gt, qpp, g0, DIM, DIM,
        (long)SEQ * DIM, 0, (long)SEQ * DIM, 1.0f, pcnt, nullptr, nullptr, 3);

    // scores: S[i,j] = q''[i,:] . kbf[j,:] / 32 -> bf16  (batch->XCD, x-fast nx=16)
    gemm_bt<true, false, true, false, 1><<<8 * 16 * 16, 256, 0, stream>>>(
        qpp, kbf, S, nullptr, SEQ, DIM,
        (long)SEQ * DIM, (long)SEQ * DIM, (long)SEQ * SEQ, 0.03125f, pcnt, nullptr, nullptr, 4);

    softmax_rows<<<BATCH * SEQ, 256, 0, stream>>>(S, pcnt);

    // out rows (scattered): per batch P @ V  (batch->XCD, y-fast ny=8)
    gemm_bt<false, false, true, true, 2><<<8 * 16 * 8, 256, 0, stream>>>(
        S, Vt, out, nullptr, DIM, SEQ,
        (long)SEQ * SEQ, (long)DIM * SEQ, (long)SEQ * DIM, 1.0f, pcnt, cnts, idx, 3);

    overwrite_masked<<<BATCH * SEQ, 256, 0, stream>>>(out, k_mask, mavg, cnts);
}

// Round 4
// 349.616 us; speedup vs baseline: 1.1491x; 1.0612x over previous
//
#include <hip/hip_runtime.h>

#define BATCH 8
#define SEQ   2048
#define DIM   1024   // D == H == 1024

typedef __attribute__((ext_vector_type(8)))  short short8;
typedef __attribute__((ext_vector_type(4)))  short short4v;
typedef __attribute__((ext_vector_type(4)))  float floatx4;
typedef __attribute__((ext_vector_type(16))) float floatx16;

__device__ __forceinline__ unsigned short f32_to_bf16(float f) {
    union { float f; unsigned int u; } x; x.f = f;
    unsigned int r = x.u + 0x7fffu + ((x.u >> 16) & 1u);
    return (unsigned short)(r >> 16);
}

__device__ __forceinline__ float bf16_to_f32(unsigned short h) {
    union { unsigned int u; float f; } x; x.u = ((unsigned int)h) << 16;
    return x.f;
}

// async 16B/lane global->LDS. LDS base wave-uniform; HW scatters lane i at base+16*i.
__device__ __forceinline__ void async_load16(const void* g, void* l) {
    __builtin_amdgcn_global_load_lds(
        (const __attribute__((address_space(1))) void*)g,
        (__attribute__((address_space(3))) void*)l, 16, 0, 0);
}

// ---------------------------------------------------------------------------
// R4 fused prep kernel. Roles by blockIdx.x:
//   [0,8):        per-batch compaction (idx/cnt/padcnt) + zero mavg[b]
//   [8,1032):     f32->bf16 convert of Wq (first 512) / Wk (next 512)
//   [1032,2056):  g0[d] = sum_h bq[h]*Wk[d,h]
// Replaces 4 launches (memset, build_idx, cvt_bf16 x2, proj_bias).
// ---------------------------------------------------------------------------
__global__ __launch_bounds__(256) void prep_misc(
    const float* __restrict__ mask, int* __restrict__ idx,
    int* __restrict__ cnt, int* __restrict__ padcnt, float* __restrict__ mavg,
    const float* __restrict__ Wq, unsigned short* __restrict__ Wqb,
    const float* __restrict__ Wk, unsigned short* __restrict__ Wkb,
    const float* __restrict__ bq, float* __restrict__ g0)
{
    __shared__ int wtot[4];
    __shared__ float rshared[4];
    const int id = blockIdx.x;
    const int t  = threadIdx.x;

    if (id < 8) {
        // ---- build_idx + mavg zero for batch b = id ----
        const int b = id;
        for (int d = t; d < DIM; d += 256) mavg[b * DIM + d] = 0.f;
        const float* mb = mask + b * SEQ;
        int flags[8]; int c = 0;
#pragma unroll
        for (int j = 0; j < 8; ++j) {
            flags[j] = (mb[t * 8 + j] > 0.5f) ? 1 : 0;
            c += flags[j];
        }
        int sc = c;                       // inclusive scan within wave
        for (int o = 1; o < 64; o <<= 1) {
            int v = __shfl_up(sc, o);
            if ((t & 63) >= o) sc += v;
        }
        const int lane = t & 63, wave = t >> 6;
        if (lane == 63) wtot[wave] = sc;
        __syncthreads();
        int woff = 0;
        for (int w = 0; w < wave; ++w) woff += wtot[w];
        int p = woff + sc - c;            // exclusive offset
#pragma unroll
        for (int j = 0; j < 8; ++j)
            if (flags[j]) idx[b * SEQ + (p++)] = t * 8 + j;
        __syncthreads();
        const int total = wtot[0] + wtot[1] + wtot[2] + wtot[3];
        if (t == 0) { cnt[b] = total; padcnt[b] = (total + 127) & ~127; }
        for (int q = total + t; q < SEQ; q += 256) idx[b * SEQ + q] = 0;
    } else if (id < 1032) {
        // ---- weight convert: 8 elems/thread ----
        const int k = id - 8;
        const float* src = (k < 512) ? Wq : Wk;
        unsigned short* dst = (k < 512) ? Wqb : Wkb;
        const long i = ((long)(k & 511) * 256 + t) * 8;
        floatx4 v0 = *(const floatx4*)(src + i);
        floatx4 v1 = *(const floatx4*)(src + i + 4);
        short8 w;
#pragma unroll
        for (int j = 0; j < 4; ++j) w[j]     = (short)f32_to_bf16(v0[j]);
#pragma unroll
        for (int j = 0; j < 4; ++j) w[4 + j] = (short)f32_to_bf16(v1[j]);
        *(short8*)(dst + i) = w;
    } else {
        // ---- proj_bias: g0[n] = sum_h bq[h]*Wk[n,h] ----
        const int n = id - 1032;
        float s = 0.f;
        for (int h = t; h < DIM; h += 256) s += bq[h] * Wk[(long)n * DIM + h];
        for (int o = 32; o; o >>= 1) s += __shfl_xor(s, o);
        if ((t & 63) == 0) rshared[t >> 6] = s;
        __syncthreads();
        if (t == 0) g0[n] = rshared[0] + rshared[1] + rshared[2] + rshared[3];
    }
}

// ---------------------------------------------------------------------------
// gather unmasked input_q rows (f32) -> compacted bf16 rows
// ---------------------------------------------------------------------------
__global__ __launch_bounds__(256) void gather_cvt_q(
    const float* __restrict__ xq, const int* __restrict__ idx,
    const int* __restrict__ padcnt, unsigned short* __restrict__ qc)
{
    const int b = blockIdx.y;
    const int rc = blockIdx.x;
    if (rc >= padcnt[b]) return;
    const int src = idx[b * SEQ + rc];
    const float* s = xq + ((long)b * SEQ + src) * DIM + threadIdx.x * 4;
    unsigned short* d = qc + ((long)b * SEQ + rc) * DIM + threadIdx.x * 4;
    floatx4 v = *(const floatx4*)s;
    short4v w;
#pragma unroll
    for (int j = 0; j < 4; ++j) w[j] = (short)f32_to_bf16(v[j]);
    *(short4v*)d = w;
}

// ---------------------------------------------------------------------------
// R4 prep_kv: 64x64 tile, float4 loads (G13), short4 stores for kbf AND Vt.
//   kbf = bf16(input_k)  (straight layout)
//   Vt  = bf16(input_k)^T per batch (DIM x SEQ)
//   mavg += masked column partial sums
// grid (DIM/64, SEQ/64, BATCH), block 256.
// ---------------------------------------------------------------------------
__global__ __launch_bounds__(256) void prep_kv(
    const float* __restrict__ xk, const float* __restrict__ mask,
    unsigned short* __restrict__ kbf, unsigned short* __restrict__ Vt,
    float* __restrict__ mavg)
{
    __shared__ float tile[64][65];
    __shared__ float msk[64];
    __shared__ float csum[4][64];
    const int b  = blockIdx.z;
    const int c0 = blockIdx.x * 64;   // dim cols
    const int r0 = blockIdx.y * 64;   // seq rows
    const int cg = threadIdx.x & 15;  // 16 col-groups x 4 cols
    const int rr = threadIdx.x >> 4;  // 0..15
    const float* xb = xk + (long)b * SEQ * DIM;
    unsigned short* kb = kbf + (long)b * SEQ * DIM;
    unsigned short* vb = Vt + (long)b * DIM * SEQ;

    if (threadIdx.x < 64) msk[threadIdx.x] = mask[b * SEQ + r0 + threadIdx.x];

    // load 4 rows/thread as float4; write kbf as short4; stash f32 in LDS
#pragma unroll
    for (int i = 0; i < 4; ++i) {
        const int row = rr + i * 16;
        const floatx4 v = *(const floatx4*)(xb + (long)(r0 + row) * DIM + c0 + cg * 4);
        short4v w;
#pragma unroll
        for (int j = 0; j < 4; ++j) {
            tile[row][cg * 4 + j] = v[j];
            w[j] = (short)f32_to_bf16(v[j]);
        }
        *(short4v*)(kb + (long)(r0 + row) * DIM + c0 + cg * 4) = w;
    }
    __syncthreads();

    // masked column partial sums: thread (rgroup, c) sums 16 rows
    {
        const int rgroup = threadIdx.x >> 6;   // 0..3
        const int c = threadIdx.x & 63;
        float s = 0.f;
#pragma unroll
        for (int r = 0; r < 16; ++r) {
            const int row = rgroup * 16 + r;
            s += (msk[row] <= 0.5f) ? tile[row][c] : 0.f;
        }
        csum[rgroup][c] = s;
    }

    // transpose write: Vt row = dim col c; short4 along seq
    {
        const int sg = threadIdx.x & 15;   // 16 seq-groups x 4
        const int ch = threadIdx.x >> 4;   // 0..15
#pragma unroll
        for (int i = 0; i < 4; ++i) {
            const int c = ch + i * 16;
            short4v w;
#pragma unroll
            for (int j = 0; j < 4; ++j) w[j] = (short)f32_to_bf16(tile[sg * 4 + j][c]);
            *(short4v*)(vb + (long)(c0 + c) * SEQ + r0 + sg * 4) = w;
        }
    }
    __syncthreads();
    if (threadIdx.x < 64) {
        const int c = threadIdx.x;
        const float tot = csum[0][c] + csum[1][c] + csum[2][c] + csum[3][c];
        atomicAdd(&mavg[b * DIM + c0 + c], tot);
    }
}

// ---------------------------------------------------------------------------
// C = A @ B^T (+bias) * scale.  A: MxK bf16, Bt: NxK bf16, C: MxN (bf16|f32).
// 128x128 block tile, BK=64, 256 threads (4 waves 2x2), each wave 64x64 via
// 2x2 v_mfma_f32_32x32x16_bf16.  XOR-swizzled LDS staging, single buffer.
// 60 VGPR + 64 AGPR = 124 regs -> 4 waves/SIMD headroom (R3).
//
// FLAT grid modes (XCD locality): 0 = normal 3D grid.
//   1 = flat 1D, batch = id&7 (pins batch->XCD), x = rem & ((1<<sh)-1), y = rem>>sh
//   2 = flat 1D, batch = id&7, y = rem & ((1<<sh)-1), x = rem>>sh
// LIMIT: skip row-blocks past mlim[z].  SCATTER: row -> idx[z][row], < cnt[z].
// MFILL (R4): blocks >= 1024 fill masked output rows with mavg/masked_count
// (replaces overwrite_masked; disjoint row sets, vectorized float4).
// ---------------------------------------------------------------------------
template<bool C_BF16, bool BIAS, bool LIMIT, bool SCATTER, int FLAT, bool MFILL>
__global__ __launch_bounds__(256, 4) void gemm_bt(
    const unsigned short* __restrict__ A, const unsigned short* __restrict__ Bt,
    void* __restrict__ Cp, const float* __restrict__ bias,
    int N, int K, long sA, long sB, long sC, float scale,
    const int* __restrict__ mlim, const int* __restrict__ cntp,
    const int* __restrict__ idx, int sh,
    const float* __restrict__ kmask, const float* __restrict__ fmavg)
{
    if (MFILL && blockIdx.x >= 1024) {      // PV grid base is fixed 8*16*8=1024
        const int id2 = blockIdx.x - 1024;  // 2048 blocks x 8 rows
        const int b = id2 >> 8;
        const int row = ((id2 & 255) << 3) + (threadIdx.x >> 5);
        if (kmask[b * SEQ + row] <= 0.5f) {
            const float inv = 1.0f / (float)(SEQ - cntp[b]);
            float* ob = (float*)Cp + ((long)b * SEQ + row) * DIM;
            const float* mv = fmavg + b * DIM;
            const int l32 = threadIdx.x & 31;
#pragma unroll
            for (int i = 0; i < 8; ++i) {
                const int d = (l32 + i * 32) * 4;
                const floatx4 s = *(const floatx4*)(mv + d);
                floatx4 o;
#pragma unroll
                for (int j = 0; j < 4; ++j) o[j] = s[j] * inv;
                *(floatx4*)(ob + d) = o;
            }
        }
        return;
    }

    int bx, by, bz;
    if (FLAT == 0) {
        bx = blockIdx.x; by = blockIdx.y; bz = blockIdx.z;
    } else {
        const int id = blockIdx.x;
        bz = id & 7;                       // batch -> XCD (round-robin heuristic)
        const int rem = id >> 3;
        const int m = (1 << sh) - 1;
        if (FLAT == 1) { bx = rem & m; by = rem >> sh; }
        else           { by = rem & m; bx = rem >> sh; }
    }
    const int row0 = bx * 128;
    if (LIMIT && row0 >= mlim[bz]) return;

    __shared__ unsigned short As[128 * 64];
    __shared__ unsigned short Bs[128 * 64];

    const int tid  = threadIdx.x;
    const int lane = tid & 63;
    const int wave = tid >> 6;
    const int wm   = wave >> 1;       // 0..1
    const int wn   = wave & 1;        // 0..1
    const int l31  = lane & 31;
    const int half = lane >> 5;       // 0..1
    const int x7   = lane & 7;
    const int col0 = by * 128;

    // staging: one async chunk = 1KB = 8 rows x 128B. lane i -> row sr=i>>3,
    // LDS slot i&7; global k-chunk sq = (i&7)^sr (XOR swizzle, in shorts*8)
    const int sr = lane >> 3;                  // 0..7
    const int sq = ((lane & 7) ^ sr) * 8;      // shorts

    const long K8 = (long)K * 8;               // 8-row stride in shorts (uniform)
    const unsigned short* aRow =
        A + (long)bz * sA + (long)row0 * K + (long)(wave * 32 + sr) * K + sq;
    const unsigned short* bRow =
        Bt + (long)bz * sB + (long)col0 * K + (long)(wave * 32 + sr) * K + sq;

    floatx16 acc[2][2];
#pragma unroll
    for (int a = 0; a < 2; ++a)
#pragma unroll
        for (int b = 0; b < 2; ++b)
#pragma unroll
            for (int r = 0; r < 16; ++r) acc[a][b][r] = 0.f;

    // fragment row bases (shorts): row stride 64
    const int raf[2] = { (wm * 64 +  0 + l31) * 64, (wm * 64 + 32 + l31) * 64 };
    const int rbf[2] = { (wn * 64 +  0 + l31) * 64, (wn * 64 + 32 + l31) * 64 };

    for (int kt = 0; kt < K; kt += 64) {
#pragma unroll
        for (int c = 0; c < 4; ++c) {
            const int chunk = wave * 4 + c;
            async_load16(aRow + kt + c * K8, As + chunk * 512);
            async_load16(bRow + kt + c * K8, Bs + chunk * 512);
        }
        __syncthreads();

#pragma unroll
        for (int ks = 0; ks < 4; ++ks) {
            const int sw = ((ks * 2 + half) ^ x7) << 3;   // swizzled 16B slot (shorts)
            short8 af[2], bf[2];
#pragma unroll
            for (int t = 0; t < 2; ++t) {
                af[t] = *(const short8*)(As + raf[t] + sw);
                bf[t] = *(const short8*)(Bs + rbf[t] + sw);
            }
#pragma unroll
            for (int tm = 0; tm < 2; ++tm)
#pragma unroll
                for (int tn = 0; tn < 2; ++tn)
                    acc[tm][tn] = __builtin_amdgcn_mfma_f32_32x32x16_bf16(
                        af[tm], bf[tn], acc[tm][tn], 0, 0, 0);
        }
        __syncthreads();
    }

    // epilogue: 32x32 C/D layout col=lane&31, row=(reg&3)+8*(reg>>2)+4*(lane>>5)
    const long zC = (long)bz * sC;
    const int climit = SCATTER ? cntp[bz] : 0;
    const int* ridx  = SCATTER ? (idx + bz * SEQ) : (const int*)nullptr;
#pragma unroll
    for (int tn = 0; tn < 2; ++tn) {
        const int ccol = col0 + wn * 64 + tn * 32 + l31;
        float bv = 0.f;
        if (BIAS) bv = bias[ccol];
#pragma unroll
        for (int tm = 0; tm < 2; ++tm) {
            const int rbase = row0 + wm * 64 + tm * 32 + 4 * half;
#pragma unroll
            for (int r = 0; r < 16; ++r) {
                const int crow = rbase + (r & 3) + 8 * (r >> 2);
                float v = acc[tm][tn][r] * scale + bv;
                long orow = crow;
                if (SCATTER) {
                    if (crow >= climit) continue;
                    orow = ridx[crow];
                }
                const long ci = zC + orow * (long)N + ccol;
                if (C_BF16) ((unsigned short*)Cp)[ci] = f32_to_bf16(v);
                else        ((float*)Cp)[ci] = v;
            }
        }
    }
}

// ---------------------------------------------------------------------------
// in-place row softmax over 2048 bf16 scores; one block per compacted row
// ---------------------------------------------------------------------------
__global__ __launch_bounds__(256) void softmax_rows(
    unsigned short* __restrict__ S, const int* __restrict__ padcnt)
{
    const int b = blockIdx.x >> 11, rc = blockIdx.x & 2047;
    if (rc >= padcnt[b]) return;
    const long base = (long)blockIdx.x * SEQ + threadIdx.x * 8;
    const int lane = threadIdx.x & 63, wave = threadIdx.x >> 6;
    __shared__ float rbuf[8];

    short8 v = *(const short8*)(S + base);
    float x[8];
#pragma unroll
    for (int j = 0; j < 8; ++j) x[j] = bf16_to_f32((unsigned short)v[j]);

    float m = x[0];
#pragma unroll
    for (int j = 1; j < 8; ++j) m = fmaxf(m, x[j]);
    for (int o = 32; o; o >>= 1) m = fmaxf(m, __shfl_xor(m, o));
    if (lane == 0) rbuf[wave] = m;
    __syncthreads();
    m = fmaxf(fmaxf(rbuf[0], rbuf[1]), fmaxf(rbuf[2], rbuf[3]));

    float e[8], s = 0.f;
#pragma unroll
    for (int j = 0; j < 8; ++j) { e[j] = __expf(x[j] - m); s += e[j]; }
    for (int o = 32; o; o >>= 1) s += __shfl_xor(s, o);
    if (lane == 0) rbuf[4 + wave] = s;
    __syncthreads();
    s = rbuf[4] + rbuf[5] + rbuf[6] + rbuf[7];
    const float inv = 1.0f / s;

    short8 o8;
#pragma unroll
    for (int j = 0; j < 8; ++j) o8[j] = (short)f32_to_bf16(e[j] * inv);
    *(short8*)(S + base) = o8;
}

extern "C" void kernel_launch(void* const* d_in, const int* in_sizes, int n_in,
                              void* d_out, int out_size, void* d_ws, size_t ws_size,
                              hipStream_t stream) {
    (void)in_sizes; (void)n_in; (void)out_size;
    const float* input_q = (const float*)d_in[0];
    const float* input_k = (const float*)d_in[1];
    const float* k_mask  = (const float*)d_in[2];
    const float* Wq      = (const float*)d_in[3];
    const float* bq      = (const float*)d_in[4];
    const float* Wk      = (const float*)d_in[5];
    const float* bk      = (const float*)d_in[6];
    (void)bk;   // bk shifts each score row by a constant -> softmax-invariant
    float* out = (float*)d_out;

    // Workspace map (aliases sequenced by stream order):
    //   qc   aliases S lo 32MB      (dead once qpp computed, before scores writes S)
    //   Wqb/Wkb alias qpp lo 4MB    (dead once Gt computed, before qpp written)
    char* ws = (char*)d_ws;
    unsigned short* qc   = (unsigned short*)(ws);                 // 32MB
    unsigned short* S    = (unsigned short*)(ws);                 // 64MB
    unsigned short* qpp  = (unsigned short*)(ws + 67108864);      // 32MB
    unsigned short* Wqb  = (unsigned short*)(ws + 67108864);      // 2MB (alias)
    unsigned short* Wkb  = (unsigned short*)(ws + 69206016);      // 2MB (alias)
    unsigned short* kbf  = (unsigned short*)(ws + 100663296);     // 32MB
    unsigned short* Vt   = (unsigned short*)(ws + 134217728);     // 32MB
    unsigned short* Gt   = (unsigned short*)(ws + 167772160);     // 2MB
    float*          g0   = (float*)(ws + 169869312);              // 4KB
    float*          mavg = (float*)(ws + 169873408);              // 32KB
    int*            idx  = (int*)(ws + 169906176);                // 64KB
    int*            cnts = (int*)(ws + 169971712);                // 32B
    int*            pcnt = (int*)(ws + 169971744);                // 32B
    if (ws_size < 169971776) return;

    // fused: memset(mavg) + build_idx + cvt(Wq,Wk) + proj_bias
    prep_misc<<<2056, 256, 0, stream>>>(k_mask, idx, cnts, pcnt, mavg,
                                        Wq, Wqb, Wk, Wkb, bq, g0);
    gather_cvt_q<<<dim3(SEQ, BATCH), 256, 0, stream>>>(input_q, idx, pcnt, qc);
    prep_kv<<<dim3(DIM / 64, SEQ / 64, BATCH), 256, 0, stream>>>(input_k, k_mask, kbf, Vt, mavg);

    // Gt[d,e] = sum_h Wk[d,h] * Wq[e,h]   (combined projection, 1024^3)
    gemm_bt<true, false, false, false, 0, false><<<dim3(8, 8, 1), 256, 0, stream>>>(
        Wkb, Wqb, Gt, nullptr, DIM, DIM, 0, 0, 0, 1.0f,
        nullptr, nullptr, nullptr, 0, nullptr, nullptr);

    // q''[m,d] = sum_e qc[m,e] * Gt[d,e] + g0[d]   (compacted; batch->XCD, y-fast ny=8)
    gemm_bt<true, true, true, false, 2, false><<<8 * 16 * 8, 256, 0, stream>>>(
        qc, Gt, qpp, g0, DIM, DIM,
        (long)SEQ * DIM, 0, (long)SEQ * DIM, 1.0f,
        pcnt, nullptr, nullptr, 3, nullptr, nullptr);

    // scores: S[i,j] = q''[i,:] . kbf[j,:] / 32 -> bf16  (batch->XCD, x-fast nx=16)
    gemm_bt<true, false, true, false, 1, false><<<8 * 16 * 16, 256, 0, stream>>>(
        qpp, kbf, S, nullptr, SEQ, DIM,
        (long)SEQ * DIM, (long)SEQ * DIM, (long)SEQ * SEQ, 0.03125f,
        pcnt, nullptr, nullptr, 4, nullptr, nullptr);

    softmax_rows<<<BATCH * SEQ, 256, 0, stream>>>(S, pcnt);

    // out rows: per batch P @ V (scattered, blocks [0,1024)) + masked-row
    // mean-fill (blocks [1024,3072), replaces overwrite_masked)
    gemm_bt<false, false, true, true, 2, true><<<1024 + 2048, 256, 0, stream>>>(
        S, Vt, out, nullptr, DIM, SEQ,
        (long)SEQ * SEQ, (long)DIM * SEQ, (long)SEQ * DIM, 1.0f,
        pcnt, cnts, idx, 3, k_mask, mavg);
}

// Round 5
// 324.694 us; speedup vs baseline: 1.2373x; 1.0768x over previous
//
#include <hip/hip_runtime.h>

#define BATCH 8
#define SEQ   2048
#define DIM   1024   // D == H == 1024

typedef __attribute__((ext_vector_type(8)))  short short8;
typedef __attribute__((ext_vector_type(4)))  short short4v;
typedef __attribute__((ext_vector_type(4)))  float floatx4;
typedef __attribute__((ext_vector_type(16))) float floatx16;

__device__ __forceinline__ unsigned short f32_to_bf16(float f) {
    union { float f; unsigned int u; } x; x.f = f;
    unsigned int r = x.u + 0x7fffu + ((x.u >> 16) & 1u);
    return (unsigned short)(r >> 16);
}

__device__ __forceinline__ float bf16_to_f32(unsigned short h) {
    union { unsigned int u; float f; } x; x.u = ((unsigned int)h) << 16;
    return x.f;
}

// async 16B/lane global->LDS. LDS base wave-uniform; HW scatters lane i at base+16*i.
__device__ __forceinline__ void async_load16(const void* g, void* l) {
    __builtin_amdgcn_global_load_lds(
        (const __attribute__((address_space(1))) void*)g,
        (__attribute__((address_space(3))) void*)l, 16, 0, 0);
}

// ---------------------------------------------------------------------------
// fused prep kernel. Roles by blockIdx.x:
//   [0,8):        per-batch compaction (idx/cnt/padcnt) + zero mavg[b]
//   [8,1032):     f32->bf16 convert of Wq (first 512) / Wk (next 512)
//   [1032,2056):  g0[d] = sum_h bq[h]*Wk[d,h]
// ---------------------------------------------------------------------------
__global__ __launch_bounds__(256) void prep_misc(
    const float* __restrict__ mask, int* __restrict__ idx,
    int* __restrict__ cnt, int* __restrict__ padcnt, float* __restrict__ mavg,
    const float* __restrict__ Wq, unsigned short* __restrict__ Wqb,
    const float* __restrict__ Wk, unsigned short* __restrict__ Wkb,
    const float* __restrict__ bq, float* __restrict__ g0)
{
    __shared__ int wtot[4];
    __shared__ float rshared[4];
    const int id = blockIdx.x;
    const int t  = threadIdx.x;

    if (id < 8) {
        // ---- build_idx + mavg zero for batch b = id ----
        const int b = id;
        for (int d = t; d < DIM; d += 256) mavg[b * DIM + d] = 0.f;
        const float* mb = mask + b * SEQ;
        int flags[8]; int c = 0;
#pragma unroll
        for (int j = 0; j < 8; ++j) {
            flags[j] = (mb[t * 8 + j] > 0.5f) ? 1 : 0;
            c += flags[j];
        }
        int sc = c;                       // inclusive scan within wave
        for (int o = 1; o < 64; o <<= 1) {
            int v = __shfl_up(sc, o);
            if ((t & 63) >= o) sc += v;
        }
        const int lane = t & 63, wave = t >> 6;
        if (lane == 63) wtot[wave] = sc;
        __syncthreads();
        int woff = 0;
        for (int w = 0; w < wave; ++w) woff += wtot[w];
        int p = woff + sc - c;            // exclusive offset
#pragma unroll
        for (int j = 0; j < 8; ++j)
            if (flags[j]) idx[b * SEQ + (p++)] = t * 8 + j;
        __syncthreads();
        const int total = wtot[0] + wtot[1] + wtot[2] + wtot[3];
        if (t == 0) { cnt[b] = total; padcnt[b] = (total + 127) & ~127; }
        for (int q = total + t; q < SEQ; q += 256) idx[b * SEQ + q] = 0;
    } else if (id < 1032) {
        // ---- weight convert: 8 elems/thread ----
        const int k = id - 8;
        const float* src = (k < 512) ? Wq : Wk;
        unsigned short* dst = (k < 512) ? Wqb : Wkb;
        const long i = ((long)(k & 511) * 256 + t) * 8;
        floatx4 v0 = *(const floatx4*)(src + i);
        floatx4 v1 = *(const floatx4*)(src + i + 4);
        short8 w;
#pragma unroll
        for (int j = 0; j < 4; ++j) w[j]     = (short)f32_to_bf16(v0[j]);
#pragma unroll
        for (int j = 0; j < 4; ++j) w[4 + j] = (short)f32_to_bf16(v1[j]);
        *(short8*)(dst + i) = w;
    } else {
        // ---- proj_bias: g0[n] = sum_h bq[h]*Wk[n,h] ----
        const int n = id - 1032;
        float s = 0.f;
        for (int h = t; h < DIM; h += 256) s += bq[h] * Wk[(long)n * DIM + h];
        for (int o = 32; o; o >>= 1) s += __shfl_xor(s, o);
        if ((t & 63) == 0) rshared[t >> 6] = s;
        __syncthreads();
        if (t == 0) g0[n] = rshared[0] + rshared[1] + rshared[2] + rshared[3];
    }
}

// ---------------------------------------------------------------------------
// 128x128 GEMM tile body (device fn).  C = A @ B^T (+bias) * scale.
// BK=64, 256 threads (4 waves 2x2), 2x2 v_mfma_f32_32x32x16_bf16 per wave.
// XOR-swizzled LDS staging, single buffer.  60 VGPR + 64 AGPR = 124 regs.
// LIMIT: skip row-blocks past mlim[z].  SCATTER: row -> idx[z][row], < cnt[z].
// ---------------------------------------------------------------------------
template<bool C_BF16, bool BIAS, bool LIMIT, bool SCATTER>
__device__ __forceinline__ void gemm_tile_128(
    unsigned short* __restrict__ As, unsigned short* __restrict__ Bs,
    int bx, int by, int bz,
    const unsigned short* __restrict__ A, const unsigned short* __restrict__ Bt,
    void* __restrict__ Cp, const float* __restrict__ bias,
    int N, int K, long sA, long sB, long sC, float scale,
    const int* __restrict__ mlim, const int* __restrict__ cntp,
    const int* __restrict__ idx)
{
    const int row0 = bx * 128;
    if (LIMIT && row0 >= mlim[bz]) return;

    const int tid  = threadIdx.x;
    const int lane = tid & 63;
    const int wave = tid >> 6;
    const int wm   = wave >> 1;       // 0..1
    const int wn   = wave & 1;        // 0..1
    const int l31  = lane & 31;
    const int half = lane >> 5;       // 0..1
    const int x7   = lane & 7;
    const int col0 = by * 128;

    // staging: one async chunk = 1KB = 8 rows x 128B. lane i -> row sr=i>>3,
    // LDS slot i&7; global k-chunk sq = (i&7)^sr (XOR swizzle, in shorts*8)
    const int sr = lane >> 3;                  // 0..7
    const int sq = ((lane & 7) ^ sr) * 8;      // shorts

    const long K8 = (long)K * 8;               // 8-row stride in shorts (uniform)
    const unsigned short* aRow =
        A + (long)bz * sA + (long)row0 * K + (long)(wave * 32 + sr) * K + sq;
    const unsigned short* bRow =
        Bt + (long)bz * sB + (long)col0 * K + (long)(wave * 32 + sr) * K + sq;

    floatx16 acc[2][2];
#pragma unroll
    for (int a = 0; a < 2; ++a)
#pragma unroll
        for (int b = 0; b < 2; ++b)
#pragma unroll
            for (int r = 0; r < 16; ++r) acc[a][b][r] = 0.f;

    // fragment row bases (shorts): row stride 64
    const int raf[2] = { (wm * 64 +  0 + l31) * 64, (wm * 64 + 32 + l31) * 64 };
    const int rbf[2] = { (wn * 64 +  0 + l31) * 64, (wn * 64 + 32 + l31) * 64 };

    for (int kt = 0; kt < K; kt += 64) {
#pragma unroll
        for (int c = 0; c < 4; ++c) {
            const int chunk = wave * 4 + c;
            async_load16(aRow + kt + c * K8, As + chunk * 512);
            async_load16(bRow + kt + c * K8, Bs + chunk * 512);
        }
        __syncthreads();

#pragma unroll
        for (int ks = 0; ks < 4; ++ks) {
            const int sw = ((ks * 2 + half) ^ x7) << 3;   // swizzled 16B slot (shorts)
            short8 af[2], bf[2];
#pragma unroll
            for (int t = 0; t < 2; ++t) {
                af[t] = *(const short8*)(As + raf[t] + sw);
                bf[t] = *(const short8*)(Bs + rbf[t] + sw);
            }
#pragma unroll
            for (int tm = 0; tm < 2; ++tm)
#pragma unroll
                for (int tn = 0; tn < 2; ++tn)
                    acc[tm][tn] = __builtin_amdgcn_mfma_f32_32x32x16_bf16(
                        af[tm], bf[tn], acc[tm][tn], 0, 0, 0);
        }
        __syncthreads();
    }

    // epilogue: 32x32 C/D layout col=lane&31, row=(reg&3)+8*(reg>>2)+4*(lane>>5)
    const long zC = (long)bz * sC;
    const int climit = SCATTER ? cntp[bz] : 0;
    const int* ridx  = SCATTER ? (idx + bz * SEQ) : (const int*)nullptr;
#pragma unroll
    for (int tn = 0; tn < 2; ++tn) {
        const int ccol = col0 + wn * 64 + tn * 32 + l31;
        float bv = 0.f;
        if (BIAS) bv = bias[ccol];
#pragma unroll
        for (int tm = 0; tm < 2; ++tm) {
            const int rbase = row0 + wm * 64 + tm * 32 + 4 * half;
#pragma unroll
            for (int r = 0; r < 16; ++r) {
                const int crow = rbase + (r & 3) + 8 * (r >> 2);
                float v = acc[tm][tn][r] * scale + bv;
                long orow = crow;
                if (SCATTER) {
                    if (crow >= climit) continue;
                    orow = ridx[crow];
                }
                const long ci = zC + orow * (long)N + ccol;
                if (C_BF16) ((unsigned short*)Cp)[ci] = f32_to_bf16(v);
                else        ((float*)Cp)[ci] = v;
            }
        }
    }
}

// ---------------------------------------------------------------------------
// GEMM kernel wrapper.  FLAT grid modes (XCD locality): 0 = normal 3D grid.
//   1 = flat 1D, batch = id&7, x = rem & ((1<<sh)-1), y = rem>>sh
//   2 = flat 1D, batch = id&7, y = rem & ((1<<sh)-1), x = rem>>sh
// MFILL: blocks >= 1024 fill masked output rows with mavg/masked_count.
// ---------------------------------------------------------------------------
template<bool C_BF16, bool BIAS, bool LIMIT, bool SCATTER, int FLAT, bool MFILL>
__global__ __launch_bounds__(256, 4) void gemm_bt(
    const unsigned short* __restrict__ A, const unsigned short* __restrict__ Bt,
    void* __restrict__ Cp, const float* __restrict__ bias,
    int N, int K, long sA, long sB, long sC, float scale,
    const int* __restrict__ mlim, const int* __restrict__ cntp,
    const int* __restrict__ idx, int sh,
    const float* __restrict__ kmask, const float* __restrict__ fmavg)
{
    __shared__ unsigned short As[128 * 64];
    __shared__ unsigned short Bs[128 * 64];

    if (MFILL && blockIdx.x >= 1024) {      // PV grid base is fixed 8*16*8=1024
        const int id2 = blockIdx.x - 1024;  // 2048 blocks x 8 rows
        const int b = id2 >> 8;
        const int row = ((id2 & 255) << 3) + (threadIdx.x >> 5);
        if (kmask[b * SEQ + row] <= 0.5f) {
            const float inv = 1.0f / (float)(SEQ - cntp[b]);
            float* ob = (float*)Cp + ((long)b * SEQ + row) * DIM;
            const float* mv = fmavg + b * DIM;
            const int l32 = threadIdx.x & 31;
#pragma unroll
            for (int i = 0; i < 8; ++i) {
                const int d = (l32 + i * 32) * 4;
                const floatx4 s = *(const floatx4*)(mv + d);
                floatx4 o;
#pragma unroll
                for (int j = 0; j < 4; ++j) o[j] = s[j] * inv;
                *(floatx4*)(ob + d) = o;
            }
        }
        return;
    }

    int bx, by, bz;
    if (FLAT == 0) {
        bx = blockIdx.x; by = blockIdx.y; bz = blockIdx.z;
    } else {
        const int id = blockIdx.x;
        bz = id & 7;                       // batch -> XCD (round-robin heuristic)
        const int rem = id >> 3;
        const int m = (1 << sh) - 1;
        if (FLAT == 1) { bx = rem & m; by = rem >> sh; }
        else           { by = rem & m; bx = rem >> sh; }
    }
    gemm_tile_128<C_BF16, BIAS, LIMIT, SCATTER>(
        As, Bs, bx, by, bz, A, Bt, Cp, bias, N, K, sA, sB, sC, scale,
        mlim, cntp, idx);
}

// ---------------------------------------------------------------------------
// R5 fused stage-2: everything that depends only on prep_misc, one launch.
//   [0,64):        Gt GEMM tiles: Gt = Wkb @ Wqb^T   (bx=id&7, by=id>>3)
//   [64,4160):     prep_kv role (64x64 tile): kbf, Vt, mavg partial sums
//   [4160,6208):   gather_cvt_q role (8 rows/block)
// Gt blocks dispatched FIRST so the compute role starts immediately while the
// memory-bound roles fill the remaining CUs.
// ---------------------------------------------------------------------------
__global__ __launch_bounds__(256, 4) void fused_stage2(
    const unsigned short* __restrict__ Wkb, const unsigned short* __restrict__ Wqb,
    unsigned short* __restrict__ Gt,
    const float* __restrict__ xq, const int* __restrict__ idx,
    const int* __restrict__ padcnt, unsigned short* __restrict__ qc,
    const float* __restrict__ xk, const float* __restrict__ mask,
    unsigned short* __restrict__ kbf, unsigned short* __restrict__ Vt,
    float* __restrict__ mavg)
{
    __shared__ unsigned short sbuf[2 * 128 * 64];   // 32 KB, shared by roles
    const int id = blockIdx.x;

    if (id < 64) {
        // ---- Gt[d,e] = sum_h Wk[d,h]*Wq[e,h]  (1024^3, 64 tiles) ----
        gemm_tile_128<true, false, false, false>(
            sbuf, sbuf + 128 * 64, id & 7, id >> 3, 0,
            Wkb, Wqb, Gt, nullptr, DIM, DIM, 0, 0, 0, 1.0f,
            nullptr, nullptr, nullptr);
    } else if (id < 64 + 4096) {
        // ---- prep_kv role: 64x64 tile, float4 loads, short4 stores ----
        const int p  = id - 64;
        const int c0 = (p & 15) * 64;          // dim cols
        const int r0 = ((p >> 4) & 31) * 64;   // seq rows
        const int b  = p >> 9;
        float* tile = (float*)sbuf;            // [64][65]
        float* msk  = tile + 64 * 65;          // [64]
        float* csum = msk + 64;                // [4][64]
        const int cg = threadIdx.x & 15;       // 16 col-groups x 4 cols
        const int rr = threadIdx.x >> 4;       // 0..15
        const float* xb = xk + (long)b * SEQ * DIM;
        unsigned short* kb = kbf + (long)b * SEQ * DIM;
        unsigned short* vb = Vt + (long)b * DIM * SEQ;

        if (threadIdx.x < 64) msk[threadIdx.x] = mask[b * SEQ + r0 + threadIdx.x];

#pragma unroll
        for (int i = 0; i < 4; ++i) {
            const int row = rr + i * 16;
            const floatx4 v = *(const floatx4*)(xb + (long)(r0 + row) * DIM + c0 + cg * 4);
            short4v w;
#pragma unroll
            for (int j = 0; j < 4; ++j) {
                tile[row * 65 + cg * 4 + j] = v[j];
                w[j] = (short)f32_to_bf16(v[j]);
            }
            *(short4v*)(kb + (long)(r0 + row) * DIM + c0 + cg * 4) = w;
        }
        __syncthreads();

        {   // masked column partial sums: thread (rgroup, c) sums 16 rows
            const int rgroup = threadIdx.x >> 6;   // 0..3
            const int c = threadIdx.x & 63;
            float s = 0.f;
#pragma unroll
            for (int r = 0; r < 16; ++r) {
                const int row = rgroup * 16 + r;
                s += (msk[row] <= 0.5f) ? tile[row * 65 + c] : 0.f;
            }
            csum[rgroup * 64 + c] = s;
        }

        {   // transpose write: Vt row = dim col c; short4 along seq
            const int sg = threadIdx.x & 15;   // 16 seq-groups x 4
            const int ch = threadIdx.x >> 4;   // 0..15
#pragma unroll
            for (int i = 0; i < 4; ++i) {
                const int c = ch + i * 16;
                short4v w;
#pragma unroll
                for (int j = 0; j < 4; ++j)
                    w[j] = (short)f32_to_bf16(tile[(sg * 4 + j) * 65 + c]);
                *(short4v*)(vb + (long)(c0 + c) * SEQ + r0 + sg * 4) = w;
            }
        }
        __syncthreads();
        if (threadIdx.x < 64) {
            const int c = threadIdx.x;
            const float tot = csum[0 * 64 + c] + csum[1 * 64 + c] +
                              csum[2 * 64 + c] + csum[3 * 64 + c];
            atomicAdd(&mavg[b * DIM + c0 + c], tot);
        }
    } else {
        // ---- gather role: 8 compacted q rows per block ----
        const int g  = id - (64 + 4096);
        const int b  = g >> 8;
        const int rc = ((g & 255) << 3) + (threadIdx.x >> 5);
        if (rc < padcnt[b]) {
            const int src = idx[b * SEQ + rc];
            const int l32 = threadIdx.x & 31;
            const float* s = xq + ((long)b * SEQ + src) * DIM;
            unsigned short* d = qc + ((long)b * SEQ + rc) * DIM;
#pragma unroll
            for (int i = 0; i < 8; ++i) {
                const int c = (l32 + i * 32) * 4;
                const floatx4 v = *(const floatx4*)(s + c);
                short4v w;
#pragma unroll
                for (int j = 0; j < 4; ++j) w[j] = (short)f32_to_bf16(v[j]);
                *(short4v*)(d + c) = w;
            }
        }
    }
}

// ---------------------------------------------------------------------------
// in-place row softmax over 2048 bf16 scores; one block per compacted row
// ---------------------------------------------------------------------------
__global__ __launch_bounds__(256) void softmax_rows(
    unsigned short* __restrict__ S, const int* __restrict__ padcnt)
{
    const int b = blockIdx.x >> 11, rc = blockIdx.x & 2047;
    if (rc >= padcnt[b]) return;
    const long base = (long)blockIdx.x * SEQ + threadIdx.x * 8;
    const int lane = threadIdx.x & 63, wave = threadIdx.x >> 6;
    __shared__ float rbuf[8];

    short8 v = *(const short8*)(S + base);
    float x[8];
#pragma unroll
    for (int j = 0; j < 8; ++j) x[j] = bf16_to_f32((unsigned short)v[j]);

    float m = x[0];
#pragma unroll
    for (int j = 1; j < 8; ++j) m = fmaxf(m, x[j]);
    for (int o = 32; o; o >>= 1) m = fmaxf(m, __shfl_xor(m, o));
    if (lane == 0) rbuf[wave] = m;
    __syncthreads();
    m = fmaxf(fmaxf(rbuf[0], rbuf[1]), fmaxf(rbuf[2], rbuf[3]));

    float e[8], s = 0.f;
#pragma unroll
    for (int j = 0; j < 8; ++j) { e[j] = __expf(x[j] - m); s += e[j]; }
    for (int o = 32; o; o >>= 1) s += __shfl_xor(s, o);
    if (lane == 0) rbuf[4 + wave] = s;
    __syncthreads();
    s = rbuf[4] + rbuf[5] + rbuf[6] + rbuf[7];
    const float inv = 1.0f / s;

    short8 o8;
#pragma unroll
    for (int j = 0; j < 8; ++j) o8[j] = (short)f32_to_bf16(e[j] * inv);
    *(short8*)(S + base) = o8;
}

extern "C" void kernel_launch(void* const* d_in, const int* in_sizes, int n_in,
                              void* d_out, int out_size, void* d_ws, size_t ws_size,
                              hipStream_t stream) {
    (void)in_sizes; (void)n_in; (void)out_size;
    const float* input_q = (const float*)d_in[0];
    const float* input_k = (const float*)d_in[1];
    const float* k_mask  = (const float*)d_in[2];
    const float* Wq      = (const float*)d_in[3];
    const float* bq      = (const float*)d_in[4];
    const float* Wk      = (const float*)d_in[5];
    const float* bk      = (const float*)d_in[6];
    (void)bk;   // bk shifts each score row by a constant -> softmax-invariant
    float* out = (float*)d_out;

    // Workspace map (aliases sequenced by stream order):
    //   qc   aliases S lo 32MB      (dead once qpp computed, before scores writes S)
    //   Wqb/Wkb alias qpp lo 4MB    (dead once Gt computed, before qpp written)
    char* ws = (char*)d_ws;
    unsigned short* qc   = (unsigned short*)(ws);                 // 32MB
    unsigned short* S    = (unsigned short*)(ws);                 // 64MB
    unsigned short* qpp  = (unsigned short*)(ws + 67108864);      // 32MB
    unsigned short* Wqb  = (unsigned short*)(ws + 67108864);      // 2MB (alias)
    unsigned short* Wkb  = (unsigned short*)(ws + 69206016);      // 2MB (alias)
    unsigned short* kbf  = (unsigned short*)(ws + 100663296);     // 32MB
    unsigned short* Vt   = (unsigned short*)(ws + 134217728);     // 32MB
    unsigned short* Gt   = (unsigned short*)(ws + 167772160);     // 2MB
    float*          g0   = (float*)(ws + 169869312);              // 4KB
    float*          mavg = (float*)(ws + 169873408);              // 32KB
    int*            idx  = (int*)(ws + 169906176);                // 64KB
    int*            cnts = (int*)(ws + 169971712);                // 32B
    int*            pcnt = (int*)(ws + 169971744);                // 32B
    if (ws_size < 169971776) return;

    // fused: memset(mavg) + build_idx + cvt(Wq,Wk) + proj_bias
    prep_misc<<<2056, 256, 0, stream>>>(k_mask, idx, cnts, pcnt, mavg,
                                        Wq, Wqb, Wk, Wkb, bq, g0);

    // fused: Gt GEMM (64 blocks, first) || prep_kv (4096) || gather_q (2048)
    fused_stage2<<<64 + 4096 + 2048, 256, 0, stream>>>(
        Wkb, Wqb, Gt, input_q, idx, pcnt, qc, input_k, k_mask, kbf, Vt, mavg);

    // q''[m,d] = sum_e qc[m,e] * Gt[d,e] + g0[d]   (compacted; batch->XCD, y-fast ny=8)
    gemm_bt<true, true, true, false, 2, false><<<8 * 16 * 8, 256, 0, stream>>>(
        qc, Gt, qpp, g0, DIM, DIM,
        (long)SEQ * DIM, 0, (long)SEQ * DIM, 1.0f,
        pcnt, nullptr, nullptr, 3, nullptr, nullptr);

    // scores: S[i,j] = q''[i,:] . kbf[j,:] / 32 -> bf16  (batch->XCD, x-fast nx=16)
    gemm_bt<true, false, true, false, 1, false><<<8 * 16 * 16, 256, 0, stream>>>(
        qpp, kbf, S, nullptr, SEQ, DIM,
        (long)SEQ * DIM, (long)SEQ * DIM, (long)SEQ * SEQ, 0.03125f,
        pcnt, nullptr, nullptr, 4, nullptr, nullptr);

    softmax_rows<<<BATCH * SEQ, 256, 0, stream>>>(S, pcnt);

    // out rows: per batch P @ V (scattered, blocks [0,1024)) + masked-row
    // mean-fill (blocks [1024,3072))
    gemm_bt<false, false, true, true, 2, true><<<1024 + 2048, 256, 0, stream>>>(
        S, Vt, out, nullptr, DIM, SEQ,
        (long)SEQ * SEQ, (long)DIM * SEQ, (long)SEQ * DIM, 1.0f,
        pcnt, cnts, idx, 3, k_mask, mavg);
}